// Round 1
// baseline (4049.875 us; speedup 1.0000x reference)
//
#include <hip/hip_runtime.h>
#include <math.h>

#define BB 16
#define NN 512
#define KNN 8
#define SEQ 12

// ---------------------------------------------------------------------------
// KNN: one thread per query point; support cloud staged in LDS.
// Produces top-8 by (d2, idx) ascending with stable tie-break (strict <),
// then applies the 3 radius masks (invalid -> nearest index).
// ---------------------------------------------------------------------------
__global__ void knn_kernel(const float* __restrict__ xq, int xq_bs,
                           const float* __restrict__ xs, int xs_bs,
                           int* __restrict__ idx1, int* __restrict__ idx2,
                           int* __restrict__ idx3,
                           float r2a, float r2b, float r2c) {
    __shared__ float s[NN * 3];
    int b = blockIdx.y;
    for (int t = threadIdx.x; t < NN * 3; t += blockDim.x)
        s[t] = xs[(long)b * xs_bs + t];
    __syncthreads();

    int n = blockIdx.x * blockDim.x + threadIdx.x;
    const float* q = xq + (long)b * xq_bs + n * 3;
    float qx = q[0], qy = q[1], qz = q[2];

    float bd[KNN];
    int   bi[KNN];
#pragma unroll
    for (int k = 0; k < KNN; ++k) { bd[k] = 1e30f; bi[k] = 0; }

    for (int j = 0; j < NN; ++j) {
        float dx = s[j * 3 + 0] - qx;
        float dy = s[j * 3 + 1] - qy;
        float dz = s[j * 3 + 2] - qz;
        float d2 = dx * dx + dy * dy + dz * dz;
        if (d2 < bd[KNN - 1]) {           // strict <: ties keep lower index
            bd[KNN - 1] = d2; bi[KNN - 1] = j;
#pragma unroll
            for (int k = KNN - 1; k >= 1; --k) {
                if (bd[k] < bd[k - 1]) {  // single bubble pass restores order
                    float td = bd[k]; bd[k] = bd[k - 1]; bd[k - 1] = td;
                    int   ti = bi[k]; bi[k] = bi[k - 1]; bi[k - 1] = ti;
                }
            }
        }
    }

    long base = ((long)(b * NN + n)) * KNN;
#pragma unroll
    for (int k = 0; k < KNN; ++k) {
        idx1[base + k] = (bd[k] <= r2a) ? bi[k] : bi[0];
        idx2[base + k] = (bd[k] <= r2b) ? bi[k] : bi[0];
        idx3[base + k] = (bd[k] <= r2c) ? bi[k] : bi[0];
    }
}

// ---------------------------------------------------------------------------
// Y[m, :cout] = X[m, :cin] @ W + bias   (W already offset to the right row
// range of the full weight; row stride = cout). 8 rows per block, one output
// column per thread, X tile in LDS.
// ---------------------------------------------------------------------------
__global__ void gemm_bias(const float* __restrict__ X, int cin,
                          const float* __restrict__ W, int cout,
                          const float* __restrict__ bias,
                          float* __restrict__ Y, int relu) {
    extern __shared__ float Xs[];
    const int ROWS = 8;
    long row0 = (long)blockIdx.x * ROWS;
    for (int t = threadIdx.x; t < ROWS * cin; t += blockDim.x)
        Xs[t] = X[row0 * cin + t];
    __syncthreads();

    int co = threadIdx.x;
    float acc[ROWS];
    float bz = bias ? bias[co] : 0.f;
#pragma unroll
    for (int r = 0; r < ROWS; ++r) acc[r] = bz;

    for (int c = 0; c < cin; ++c) {
        float w = W[(long)c * cout + co];
#pragma unroll
        for (int r = 0; r < ROWS; ++r)
            acc[r] = fmaf(Xs[r * cin + c], w, acc[r]);
    }
#pragma unroll
    for (int r = 0; r < ROWS; ++r) {
        float v = acc[r];
        if (relu) v = fmaxf(v, 0.f);
        Y[(row0 + r) * cout + co] = v;
    }
}

// ---------------------------------------------------------------------------
// out[b,n,co] = max_k( base(or bias) + disp_k . Wd[:,co] + G[b, idx_k, co] )
// One block per (b,n), one thread per output column.
// ---------------------------------------------------------------------------
__global__ void combine_kernel(const float* __restrict__ xq, int xq_bs,
                               const float* __restrict__ xs, int xs_bs,
                               const int* __restrict__ idx,
                               const float* __restrict__ G,
                               const float* __restrict__ base,
                               const float* __restrict__ bias,
                               const float* __restrict__ Wd, int cout,
                               float* __restrict__ out) {
    __shared__ float ds[KNN][3];
    __shared__ int   js[KNN];
    int b = blockIdx.y, n = blockIdx.x;
    long pn = (long)b * NN + n;
    if (threadIdx.x < KNN) {
        int j = idx[pn * KNN + threadIdx.x];
        js[threadIdx.x] = j;
        const float* sp = xs + (long)b * xs_bs + j * 3;
        const float* qp = xq + (long)b * xq_bs + n * 3;
        ds[threadIdx.x][0] = sp[0] - qp[0];
        ds[threadIdx.x][1] = sp[1] - qp[1];
        ds[threadIdx.x][2] = sp[2] - qp[2];
    }
    __syncthreads();

    int co = threadIdx.x;
    float wx = Wd[co], wy = Wd[cout + co], wz = Wd[2 * cout + co];
    float bv = base ? base[pn * cout + co] : bias[co];
    float acc = -1e30f;
#pragma unroll
    for (int k = 0; k < KNN; ++k) {
        float v = fmaf(ds[k][0], wx, bv);
        v = fmaf(ds[k][1], wy, v);
        v = fmaf(ds[k][2], wz, v);
        if (G) v += G[((long)b * NN + js[k]) * cout + co];
        acc = fmaxf(acc, v);
    }
    out[pn * cout + co] = acc;
}

// ---------------------------------------------------------------------------
// x_next[b,n,:] = x_prev[b,n,:] + h[b,n,:64] @ Wl + bl
// One wave (64 lanes) per point; 4 points per 256-thread block.
// ---------------------------------------------------------------------------
__global__ void motion_kernel(const float* __restrict__ h,
                              const float* __restrict__ Wl,
                              const float* __restrict__ bl,
                              const float* __restrict__ xprev, int xp_bs,
                              float* __restrict__ xnext, int xn_bs) {
    int lane = threadIdx.x & 63;
    int wave = threadIdx.x >> 6;
    int p = blockIdx.x * 4 + wave;       // [0, B*N)
    int b = p / NN, n = p % NN;
    float hv = h[(long)p * 64 + lane];
    float m0 = hv * Wl[lane * 3 + 0];
    float m1 = hv * Wl[lane * 3 + 1];
    float m2 = hv * Wl[lane * 3 + 2];
#pragma unroll
    for (int off = 32; off >= 1; off >>= 1) {
        m0 += __shfl_down(m0, off, 64);
        m1 += __shfl_down(m1, off, 64);
        m2 += __shfl_down(m2, off, 64);
    }
    if (lane == 0) {
        const float* xp = xprev + (long)b * xp_bs + n * 3;
        float* xn = xnext + (long)b * xn_bs + n * 3;
        xn[0] = xp[0] + m0 + bl[0];
        xn[1] = xp[1] + m1 + bl[1];
        xn[2] = xp[2] + m2 + bl[2];
    }
}

extern "C" void kernel_launch(void* const* d_in, const int* in_sizes, int n_in,
                              void* d_out, int out_size, void* d_ws, size_t ws_size,
                              hipStream_t stream) {
    const float* frames = (const float*)d_in[0];
    const float* W1 = (const float*)d_in[1]; const float* b1 = (const float*)d_in[2];
    const float* W2 = (const float*)d_in[3]; const float* b2 = (const float*)d_in[4];
    const float* W3 = (const float*)d_in[5]; const float* b3 = (const float*)d_in[6];
    const float* Wm = (const float*)d_in[7]; const float* bm = (const float*)d_in[8];
    const float* Wl = (const float*)d_in[9]; const float* bl = (const float*)d_in[10];
    float* out = (float*)d_out;

    // workspace carve-up (floats)
    float* ws = (float*)d_ws;
    float* s1    = ws; ws += (size_t)BB * NN * 64;
    float* s2    = ws; ws += (size_t)BB * NN * 128;
    float* s3    = ws; ws += (size_t)BB * NN * 256;
    float* G1    = ws; ws += (size_t)BB * NN * 64;
    float* G2    = ws; ws += (size_t)BB * NN * 128;
    float* G3    = ws; ws += (size_t)BB * NN * 256;
    float* base2 = ws; ws += (size_t)BB * NN * 128;
    float* base3 = ws; ws += (size_t)BB * NN * 256;
    float* hbuf  = ws; ws += (size_t)BB * NN * 64;
    int* idx1 = (int*)ws; ws += (size_t)BB * NN * KNN;
    int* idx2 = (int*)ws; ws += (size_t)BB * NN * KNN;
    int* idx3 = (int*)ws; ws += (size_t)BB * NN * KNN;

    // radius^2 thresholds, computed in double then rounded (matches JAX weak-type)
    double ra = 4.0 + 1e-6, rb = 8.0 + 1e-6, rc = 12.0 + 1e-6;
    float r2a = (float)(ra * ra), r2b = (float)(rb * rb), r2c = (float)(rc * rc);

    const int FB = SEQ * NN * 3;  // frames batch stride
    const int OB = 6 * NN * 3;    // output batch stride

    for (int t = 0; t < SEQ; ++t) {
        // query / support pointer schedule
        const float* xq; int xq_bs;
        const float* xs; int xs_bs;
        if (t < 6)       { xq = frames + (long)t * NN * 3;        xq_bs = FB; }
        else if (t == 6) { xq = frames + 5L * NN * 3;             xq_bs = FB; }
        else             { xq = out + (long)(t - 7) * NN * 3;     xq_bs = OB; }
        if (t == 0)      { xs = xq;                               xs_bs = xq_bs; }
        else if (t <= 6) { xs = frames + (long)(t - 1) * NN * 3;  xs_bs = FB; }
        else if (t == 7) { xs = frames + 5L * NN * 3;             xs_bs = FB; }
        else             { xs = out + (long)(t - 8) * NN * 3;     xs_bs = OB; }

        bool first = (t == 0);

        // one KNN per step feeds all three cells (same geometry, 3 radii)
        knn_kernel<<<dim3(NN / 256, BB), 256, 0, stream>>>(
            xq, xq_bs, xs, xs_bs, idx1, idx2, idx3, r2a, r2b, r2c);

        // ---- cell 1 (feat=None; W1: [disp 0..2 | n_feat 3..66] x 64) ----
        if (!first)
            gemm_bias<<<BB * NN / 8, 64, 8 * 64 * 4, stream>>>(
                s1, 64, W1 + 3 * 64, 64, nullptr, G1, 0);
        combine_kernel<<<dim3(NN, BB), 64, 0, stream>>>(
            xq, xq_bs, xs, xs_bs, idx1, first ? nullptr : G1,
            nullptr, b1, W1, 64, s1);

        // ---- cell 2 (W2: [disp 0..2 | feat 3..66 | n_feat 67..194] x 128) ----
        if (!first)
            gemm_bias<<<BB * NN / 8, 128, 8 * 128 * 4, stream>>>(
                s2, 128, W2 + 67 * 128, 128, nullptr, G2, 0);
        gemm_bias<<<BB * NN / 8, 128, 8 * 64 * 4, stream>>>(
            s1, 64, W2 + 3 * 128, 128, b2, base2, 0);
        combine_kernel<<<dim3(NN, BB), 128, 0, stream>>>(
            xq, xq_bs, xs, xs_bs, idx2, first ? nullptr : G2,
            base2, nullptr, W2, 128, s2);

        // ---- cell 3 (W3: [disp 0..2 | feat 3..130 | n_feat 131..386] x 256) ----
        if (!first)
            gemm_bias<<<BB * NN / 8, 256, 8 * 256 * 4, stream>>>(
                s3, 256, W3 + 131 * 256, 256, nullptr, G3, 0);
        gemm_bias<<<BB * NN / 8, 256, 8 * 128 * 4, stream>>>(
            s2, 128, W3 + 3 * 256, 256, b3, base3, 0);
        combine_kernel<<<dim3(NN, BB), 256, 0, stream>>>(
            xq, xq_bs, xs, xs_bs, idx3, first ? nullptr : G3,
            base3, nullptr, W3, 256, s3);

        // ---- prediction head (steps 6..11) ----
        if (t >= 6) {
            gemm_bias<<<BB * NN / 8, 64, 8 * 256 * 4, stream>>>(
                s3, 256, Wm, 64, bm, hbuf, 1);
            motion_kernel<<<BB * NN / 4, 256, 0, stream>>>(
                hbuf, Wl, bl, xq, xq_bs, out + (long)(t - 6) * NN * 3, OB);
        }
    }
}

// Round 2
// 2186.700 us; speedup vs baseline: 1.8520x; 1.8520x over previous
//
#include <hip/hip_runtime.h>
#include <math.h>

#define BB 16
#define NN 512
#define KNN 8
#define SEQ 12
#define TQ 8            // threads per query (each scans NN/TQ support points)
#define QB 32           // queries per block (TQ*QB = 256 threads)

// ---------------------------------------------------------------------------
// KNN: 8 threads per query, each keeps a local top-8 over a 64-point chunk,
// then thread sub==0 merges the 8 sorted partial lists (chunk-major, strict-<
// insertion => stable (d2, idx) ordering identical to a serial scan).
// ---------------------------------------------------------------------------
__global__ void knn_kernel(const float* __restrict__ xq, int xq_bs,
                           const float* __restrict__ xs, int xs_bs,
                           int* __restrict__ idx1, int* __restrict__ idx2,
                           int* __restrict__ idx3,
                           float r2a, float r2b, float r2c) {
    __shared__ float s[NN * 3];
    __shared__ float cd[QB][TQ][KNN];
    __shared__ int   ci[QB][TQ][KNN];
    int b = blockIdx.y;
    for (int t = threadIdx.x; t < NN * 3; t += blockDim.x)
        s[t] = xs[(long)b * xs_bs + t];
    __syncthreads();

    int qi  = threadIdx.x / TQ;     // query slot within block
    int sub = threadIdx.x % TQ;     // chunk id
    int n = blockIdx.x * QB + qi;
    const float* q = xq + (long)b * xq_bs + n * 3;
    float qx = q[0], qy = q[1], qz = q[2];

    float bd[KNN];
    int   bi[KNN];
#pragma unroll
    for (int k = 0; k < KNN; ++k) { bd[k] = 1e30f; bi[k] = 0; }

    int j0 = sub * (NN / TQ);
    for (int jj = 0; jj < NN / TQ; ++jj) {
        int j = j0 + jj;
        float dx = s[j * 3 + 0] - qx;
        float dy = s[j * 3 + 1] - qy;
        float dz = s[j * 3 + 2] - qz;
        float d2 = dx * dx + dy * dy + dz * dz;
        if (d2 < bd[KNN - 1]) {          // strict <: ties keep lower index
            bd[KNN - 1] = d2; bi[KNN - 1] = j;
#pragma unroll
            for (int k = KNN - 1; k >= 1; --k) {
                if (bd[k] < bd[k - 1]) {
                    float td = bd[k]; bd[k] = bd[k - 1]; bd[k - 1] = td;
                    int   ti = bi[k]; bi[k] = bi[k - 1]; bi[k - 1] = ti;
                }
            }
        }
    }

#pragma unroll
    for (int k = 0; k < KNN; ++k) { cd[qi][sub][k] = bd[k]; ci[qi][sub][k] = bi[k]; }
    __syncthreads();

    if (sub == 0) {
        float md[KNN];
        int   mi[KNN];
#pragma unroll
        for (int k = 0; k < KNN; ++k) { md[k] = 1e30f; mi[k] = 0; }
        // chunk-major merge: candidate index order is globally ascending for
        // ties (chunk t's indices < chunk t+1's), strict < keeps stability
        for (int t2 = 0; t2 < TQ; ++t2) {
#pragma unroll
            for (int k2 = 0; k2 < KNN; ++k2) {
                float d2 = cd[qi][t2][k2];
                int   j  = ci[qi][t2][k2];
                if (d2 < md[KNN - 1]) {
                    md[KNN - 1] = d2; mi[KNN - 1] = j;
#pragma unroll
                    for (int k = KNN - 1; k >= 1; --k) {
                        if (md[k] < md[k - 1]) {
                            float td = md[k]; md[k] = md[k - 1]; md[k - 1] = td;
                            int   ti = mi[k]; mi[k] = mi[k - 1]; mi[k - 1] = ti;
                        }
                    }
                }
            }
        }
        long base = ((long)(b * NN + n)) * KNN;
#pragma unroll
        for (int k = 0; k < KNN; ++k) {
            idx1[base + k] = (md[k] <= r2a) ? mi[k] : mi[0];
            idx2[base + k] = (md[k] <= r2b) ? mi[k] : mi[0];
            idx3[base + k] = (md[k] <= r2c) ? mi[k] : mi[0];
        }
    }
}

// ---------------------------------------------------------------------------
// Y[m, :cout] = X[m, :cin] @ W + bias   (W already offset to the right row
// range of the full weight; row stride = cout). 8 rows per block, one output
// column per thread, X tile in LDS, float4 LDS reads (ds_read_b128).
// ---------------------------------------------------------------------------
__global__ void gemm_bias(const float* __restrict__ X, int cin,
                          const float* __restrict__ W, int cout,
                          const float* __restrict__ bias,
                          float* __restrict__ Y, int relu) {
    extern __shared__ float Xs[];
    const int ROWS = 8;
    long row0 = (long)blockIdx.x * ROWS;
    const float4* Xg4 = (const float4*)(X + row0 * cin);
    float4* Xs4 = (float4*)Xs;
    for (int t = threadIdx.x; t < ROWS * cin / 4; t += blockDim.x)
        Xs4[t] = Xg4[t];
    __syncthreads();

    int co = threadIdx.x;
    float acc[ROWS];
    float bz = bias ? bias[co] : 0.f;
#pragma unroll
    for (int r = 0; r < ROWS; ++r) acc[r] = bz;

    for (int c = 0; c < cin; c += 4) {
        float w0 = W[(long)c * cout + co];
        float w1 = W[(long)(c + 1) * cout + co];
        float w2 = W[(long)(c + 2) * cout + co];
        float w3 = W[(long)(c + 3) * cout + co];
#pragma unroll
        for (int r = 0; r < ROWS; ++r) {
            float4 x = Xs4[(r * cin + c) >> 2];
            acc[r] = fmaf(x.x, w0, acc[r]);
            acc[r] = fmaf(x.y, w1, acc[r]);
            acc[r] = fmaf(x.z, w2, acc[r]);
            acc[r] = fmaf(x.w, w3, acc[r]);
        }
    }
#pragma unroll
    for (int r = 0; r < ROWS; ++r) {
        float v = acc[r];
        if (relu) v = fmaxf(v, 0.f);
        Y[(row0 + r) * cout + co] = v;
    }
}

// ---------------------------------------------------------------------------
// out[b,n,co] = max_k( base(or bias) + disp_k . Wd[:,co] + G[b, idx_k, co] )
// One block per (b,n), one thread per output column.
// ---------------------------------------------------------------------------
__global__ void combine_kernel(const float* __restrict__ xq, int xq_bs,
                               const float* __restrict__ xs, int xs_bs,
                               const int* __restrict__ idx,
                               const float* __restrict__ G,
                               const float* __restrict__ base,
                               const float* __restrict__ bias,
                               const float* __restrict__ Wd, int cout,
                               float* __restrict__ out) {
    __shared__ float ds[KNN][3];
    __shared__ int   js[KNN];
    int b = blockIdx.y, n = blockIdx.x;
    long pn = (long)b * NN + n;
    if (threadIdx.x < KNN) {
        int j = idx[pn * KNN + threadIdx.x];
        js[threadIdx.x] = j;
        const float* sp = xs + (long)b * xs_bs + j * 3;
        const float* qp = xq + (long)b * xq_bs + n * 3;
        ds[threadIdx.x][0] = sp[0] - qp[0];
        ds[threadIdx.x][1] = sp[1] - qp[1];
        ds[threadIdx.x][2] = sp[2] - qp[2];
    }
    __syncthreads();

    int co = threadIdx.x;
    float wx = Wd[co], wy = Wd[cout + co], wz = Wd[2 * cout + co];
    float bv = base ? base[pn * cout + co] : bias[co];
    float acc = -1e30f;
#pragma unroll
    for (int k = 0; k < KNN; ++k) {
        float v = fmaf(ds[k][0], wx, bv);
        v = fmaf(ds[k][1], wy, v);
        v = fmaf(ds[k][2], wz, v);
        if (G) v += G[((long)b * NN + js[k]) * cout + co];
        acc = fmaxf(acc, v);
    }
    out[pn * cout + co] = acc;
}

// ---------------------------------------------------------------------------
// x_next[b,n,:] = x_prev[b,n,:] + h[b,n,:64] @ Wl + bl
// One wave (64 lanes) per point; 4 points per 256-thread block.
// ---------------------------------------------------------------------------
__global__ void motion_kernel(const float* __restrict__ h,
                              const float* __restrict__ Wl,
                              const float* __restrict__ bl,
                              const float* __restrict__ xprev, int xp_bs,
                              float* __restrict__ xnext, int xn_bs) {
    int lane = threadIdx.x & 63;
    int wave = threadIdx.x >> 6;
    int p = blockIdx.x * 4 + wave;       // [0, B*N)
    int b = p / NN, n = p % NN;
    float hv = h[(long)p * 64 + lane];
    float m0 = hv * Wl[lane * 3 + 0];
    float m1 = hv * Wl[lane * 3 + 1];
    float m2 = hv * Wl[lane * 3 + 2];
#pragma unroll
    for (int off = 32; off >= 1; off >>= 1) {
        m0 += __shfl_down(m0, off, 64);
        m1 += __shfl_down(m1, off, 64);
        m2 += __shfl_down(m2, off, 64);
    }
    if (lane == 0) {
        const float* xp = xprev + (long)b * xp_bs + n * 3;
        float* xn = xnext + (long)b * xn_bs + n * 3;
        xn[0] = xp[0] + m0 + bl[0];
        xn[1] = xp[1] + m1 + bl[1];
        xn[2] = xp[2] + m2 + bl[2];
    }
}

extern "C" void kernel_launch(void* const* d_in, const int* in_sizes, int n_in,
                              void* d_out, int out_size, void* d_ws, size_t ws_size,
                              hipStream_t stream) {
    const float* frames = (const float*)d_in[0];
    const float* W1 = (const float*)d_in[1]; const float* b1 = (const float*)d_in[2];
    const float* W2 = (const float*)d_in[3]; const float* b2 = (const float*)d_in[4];
    const float* W3 = (const float*)d_in[5]; const float* b3 = (const float*)d_in[6];
    const float* Wm = (const float*)d_in[7]; const float* bm = (const float*)d_in[8];
    const float* Wl = (const float*)d_in[9]; const float* bl = (const float*)d_in[10];
    float* out = (float*)d_out;

    // workspace carve-up (floats)
    float* ws = (float*)d_ws;
    float* s1    = ws; ws += (size_t)BB * NN * 64;
    float* s2    = ws; ws += (size_t)BB * NN * 128;
    float* s3    = ws; ws += (size_t)BB * NN * 256;
    float* G1    = ws; ws += (size_t)BB * NN * 64;
    float* G2    = ws; ws += (size_t)BB * NN * 128;
    float* G3    = ws; ws += (size_t)BB * NN * 256;
    float* base2 = ws; ws += (size_t)BB * NN * 128;
    float* base3 = ws; ws += (size_t)BB * NN * 256;
    float* hbuf  = ws; ws += (size_t)BB * NN * 64;
    int* idx1 = (int*)ws; ws += (size_t)BB * NN * KNN;
    int* idx2 = (int*)ws; ws += (size_t)BB * NN * KNN;
    int* idx3 = (int*)ws; ws += (size_t)BB * NN * KNN;

    // radius^2 thresholds, computed in double then rounded (matches JAX weak-type)
    double ra = 4.0 + 1e-6, rb = 8.0 + 1e-6, rc = 12.0 + 1e-6;
    float r2a = (float)(ra * ra), r2b = (float)(rb * rb), r2c = (float)(rc * rc);

    const int FB = SEQ * NN * 3;  // frames batch stride
    const int OB = 6 * NN * 3;    // output batch stride

    for (int t = 0; t < SEQ; ++t) {
        // query / support pointer schedule
        const float* xq; int xq_bs;
        const float* xs; int xs_bs;
        if (t < 6)       { xq = frames + (long)t * NN * 3;        xq_bs = FB; }
        else if (t == 6) { xq = frames + 5L * NN * 3;             xq_bs = FB; }
        else             { xq = out + (long)(t - 7) * NN * 3;     xq_bs = OB; }
        if (t == 0)      { xs = xq;                               xs_bs = xq_bs; }
        else if (t <= 6) { xs = frames + (long)(t - 1) * NN * 3;  xs_bs = FB; }
        else if (t == 7) { xs = frames + 5L * NN * 3;             xs_bs = FB; }
        else             { xs = out + (long)(t - 8) * NN * 3;     xs_bs = OB; }

        bool first = (t == 0);

        // one KNN per step feeds all three cells (same geometry, 3 radii)
        knn_kernel<<<dim3(NN / QB, BB), QB * TQ, 0, stream>>>(
            xq, xq_bs, xs, xs_bs, idx1, idx2, idx3, r2a, r2b, r2c);

        // ---- cell 1 (feat=None; W1: [disp 0..2 | n_feat 3..66] x 64) ----
        if (!first)
            gemm_bias<<<BB * NN / 8, 64, 8 * 64 * 4, stream>>>(
                s1, 64, W1 + 3 * 64, 64, nullptr, G1, 0);
        combine_kernel<<<dim3(NN, BB), 64, 0, stream>>>(
            xq, xq_bs, xs, xs_bs, idx1, first ? nullptr : G1,
            nullptr, b1, W1, 64, s1);

        // ---- cell 2 (W2: [disp 0..2 | feat 3..66 | n_feat 67..194] x 128) ----
        if (!first)
            gemm_bias<<<BB * NN / 8, 128, 8 * 128 * 4, stream>>>(
                s2, 128, W2 + 67 * 128, 128, nullptr, G2, 0);
        gemm_bias<<<BB * NN / 8, 128, 8 * 64 * 4, stream>>>(
            s1, 64, W2 + 3 * 128, 128, b2, base2, 0);
        combine_kernel<<<dim3(NN, BB), 128, 0, stream>>>(
            xq, xq_bs, xs, xs_bs, idx2, first ? nullptr : G2,
            base2, nullptr, W2, 128, s2);

        // ---- cell 3 (W3: [disp 0..2 | feat 3..130 | n_feat 131..386] x 256) ----
        if (!first)
            gemm_bias<<<BB * NN / 8, 256, 8 * 256 * 4, stream>>>(
                s3, 256, W3 + 131 * 256, 256, nullptr, G3, 0);
        gemm_bias<<<BB * NN / 8, 256, 8 * 128 * 4, stream>>>(
            s2, 128, W3 + 3 * 256, 256, b3, base3, 0);
        combine_kernel<<<dim3(NN, BB), 256, 0, stream>>>(
            xq, xq_bs, xs, xs_bs, idx3, first ? nullptr : G3,
            base3, nullptr, W3, 256, s3);

        // ---- prediction head (steps 6..11) ----
        if (t >= 6) {
            gemm_bias<<<BB * NN / 8, 64, 8 * 256 * 4, stream>>>(
                s3, 256, Wm, 64, bm, hbuf, 1);
            motion_kernel<<<BB * NN / 4, 256, 0, stream>>>(
                hbuf, Wl, bl, xq, xq_bs, out + (long)(t - 6) * NN * 3, OB);
        }
    }
}

// Round 3
// 1397.644 us; speedup vs baseline: 2.8976x; 1.5646x over previous
//
#include <hip/hip_runtime.h>
#include <math.h>

#define BB 16
#define NN 512
#define KNN 8
#define SEQ 12
#define TQ 8            // threads per query (each scans NN/TQ support points)
#define QB 32           // queries per block (TQ*QB = 256 threads)

// ---------------------------------------------------------------------------
// KNN. LDS layout: point j at s[3j + (j>>6)] -> per-chunk +1 float pad, so the
// wave's 8 concurrent sub-chunk reads hit 8 distinct banks (each an 8-lane
// broadcast) instead of one bank 8-way. Partial top-8 per thread, then a
// 3-level pairwise tree merge with (d2, idx) lexicographic compares (exactly
// stable top-k). warm=1: blockIdx.z = step t in 0..6, pointers derived from
// frames; outputs offset by z*B*N*K.
// ---------------------------------------------------------------------------
__global__ __launch_bounds__(256) void knn_kernel(
        const float* __restrict__ xq, int xq_bs,
        const float* __restrict__ xs, int xs_bs,
        int* __restrict__ idx1, int* __restrict__ idx2, int* __restrict__ idx3,
        float r2a, float r2b, float r2c, int warm) {
    __shared__ float s[NN * 3 + NN / 64];
    __shared__ float cd[QB][TQ][KNN + 1];
    __shared__ int   ci[QB][TQ][KNN + 1];
    int b = blockIdx.y;
    const float* xqp; const float* xsp; long iofs;
    if (warm) {
        int z = blockIdx.z;
        int qz = z < 5 ? z : 5;
        int sz = z - 1 < 0 ? 0 : z - 1;
        xqp = xq + (long)qz * NN * 3;
        xsp = xq + (long)sz * NN * 3;
        xs_bs = xq_bs;
        iofs = (long)z * BB * NN * KNN;
    } else {
        xqp = xq; xsp = xs; iofs = 0;
    }

    for (int j = threadIdx.x; j < NN; j += 256) {
        const float* p = xsp + (long)b * xs_bs + j * 3;
        int o = 3 * j + (j >> 6);
        s[o + 0] = p[0]; s[o + 1] = p[1]; s[o + 2] = p[2];
    }
    __syncthreads();

    int qi  = threadIdx.x / TQ;
    int sub = threadIdx.x % TQ;
    int n = blockIdx.x * QB + qi;
    const float* q = xqp + (long)b * xq_bs + n * 3;
    float qx = q[0], qy = q[1], qz2 = q[2];

    float bd[KNN];
    int   bi[KNN];
#pragma unroll
    for (int k = 0; k < KNN; ++k) { bd[k] = 1e30f; bi[k] = 0; }

    int j0 = sub * (NN / TQ);
    int sbase = 3 * j0 + sub;            // (j>>6)==sub within this chunk
#pragma unroll 4
    for (int jj = 0; jj < NN / TQ; ++jj) {
        float dx = s[sbase + 3 * jj + 0] - qx;
        float dy = s[sbase + 3 * jj + 1] - qy;
        float dz = s[sbase + 3 * jj + 2] - qz2;
        float d2 = fmaf(dx, dx, fmaf(dy, dy, dz * dz));
        if (d2 < bd[KNN - 1]) {          // strict <: ties keep lower index
            bd[KNN - 1] = d2; bi[KNN - 1] = j0 + jj;
#pragma unroll
            for (int k = KNN - 1; k >= 1; --k) {
                if (bd[k] < bd[k - 1]) {
                    float td = bd[k]; bd[k] = bd[k - 1]; bd[k - 1] = td;
                    int   ti = bi[k]; bi[k] = bi[k - 1]; bi[k - 1] = ti;
                }
            }
        }
    }

#pragma unroll
    for (int k = 0; k < KNN; ++k) { cd[qi][sub][k] = bd[k]; ci[qi][sub][k] = bi[k]; }
    cd[qi][sub][KNN] = 1e30f; ci[qi][sub][KNN] = 0x7fffffff;  // sentinel
    __syncthreads();

    // pairwise tree merge, lexicographic (d2, idx) -> exact stable top-8
    for (int stride = TQ / 2; stride >= 1; stride >>= 1) {
        if (sub < stride) {
            float rd[KNN]; int ri[KNN];
            int ia = 0, ib = 0;
#pragma unroll
            for (int k = 0; k < KNN; ++k) {
                float da = cd[qi][sub][ia], db = cd[qi][sub + stride][ib];
                int   ja = ci[qi][sub][ia], jb = ci[qi][sub + stride][ib];
                bool ta = (da < db) || (da == db && ja < jb);
                rd[k] = ta ? da : db; ri[k] = ta ? ja : jb;
                ia += ta ? 1 : 0; ib += ta ? 0 : 1;
            }
#pragma unroll
            for (int k = 0; k < KNN; ++k) { cd[qi][sub][k] = rd[k]; ci[qi][sub][k] = ri[k]; }
        }
        __syncthreads();
    }

    if (sub == 0) {
        long base = iofs + ((long)(b * NN + n)) * KNN;
        int i0 = ci[qi][0][0];
#pragma unroll
        for (int k = 0; k < KNN; ++k) {
            float d = cd[qi][0][k]; int j = ci[qi][0][k];
            idx1[base + k] = (d <= r2a) ? j : i0;
            idx2[base + k] = (d <= r2b) ? j : i0;
            idx3[base + k] = (d <= r2c) ? j : i0;
        }
    }
}

// ---------------------------------------------------------------------------
// 16-rows-per-block GEMM, 256 threads. GROUPS = 256/COUT thread groups each
// handle 16/GROUPS rows -> all 256 threads busy for COUT in {64,128,256}.
// X tile in dynamic LDS (float4, wave-broadcast reads); W columns from L2,
// amortized over 16 rows.
// ---------------------------------------------------------------------------
template<int CIN, int COUT>
__device__ __forceinline__ void gemm16(const float* __restrict__ X,
                                       const float* __restrict__ W,
                                       const float* __restrict__ bias,
                                       float* __restrict__ Y, int relu, int blk) {
    constexpr int GROUPS = 256 / COUT;
    constexpr int RPT = 16 / GROUPS;
    extern __shared__ float Xs[];
    float4* Xs4 = (float4*)Xs;
    long row0 = (long)blk * 16;
    const float4* Xg4 = (const float4*)(X + row0 * CIN);
    for (int t = threadIdx.x; t < 16 * CIN / 4; t += 256) Xs4[t] = Xg4[t];
    __syncthreads();

    int g = threadIdx.x / COUT, co = threadIdx.x % COUT;
    int r0 = g * RPT;
    float bz = bias ? bias[co] : 0.f;
    float acc[RPT];
#pragma unroll
    for (int r = 0; r < RPT; ++r) acc[r] = bz;

    for (int c = 0; c < CIN; c += 4) {
        float w0 = W[(long)(c + 0) * COUT + co];
        float w1 = W[(long)(c + 1) * COUT + co];
        float w2 = W[(long)(c + 2) * COUT + co];
        float w3 = W[(long)(c + 3) * COUT + co];
#pragma unroll
        for (int r = 0; r < RPT; ++r) {
            float4 x = Xs4[((r0 + r) * CIN + c) >> 2];
            acc[r] = fmaf(x.x, w0, acc[r]);
            acc[r] = fmaf(x.y, w1, acc[r]);
            acc[r] = fmaf(x.z, w2, acc[r]);
            acc[r] = fmaf(x.w, w3, acc[r]);
        }
    }
#pragma unroll
    for (int r = 0; r < RPT; ++r) {
        float v = acc[r];
        if (relu) v = fmaxf(v, 0.f);
        Y[(row0 + r0 + r) * COUT + co] = v;
    }
}

template<int CIN, int COUT>
__global__ __launch_bounds__(256) void gemm16_kernel(
        const float* __restrict__ X, const float* __restrict__ W,
        const float* __restrict__ bias, float* __restrict__ Y, int relu) {
    gemm16<CIN, COUT>(X, W, bias, Y, relu, blockIdx.x);
}

// G1 + G2 + G3 fused into one dispatch (independent of each other)
__global__ __launch_bounds__(256) void multiG_kernel(
        const float* __restrict__ s1, const float* __restrict__ W1n,
        const float* __restrict__ s2, const float* __restrict__ W2n,
        const float* __restrict__ s3, const float* __restrict__ W3n,
        float* __restrict__ G1, float* __restrict__ G2, float* __restrict__ G3) {
    const int nb = BB * NN / 16;   // 512 blocks per segment
    int bx = blockIdx.x;
    if (bx < nb)            gemm16<64, 64>  (s1, W1n, nullptr, G1, 0, bx);
    else if (bx < 2 * nb)   gemm16<128, 128>(s2, W2n, nullptr, G2, 0, bx - nb);
    else                    gemm16<256, 256>(s3, W3n, nullptr, G3, 0, bx - 2 * nb);
}

// ---------------------------------------------------------------------------
// out[b,n,co] = max_k( base(or bias) + disp_k . Wd[:,co] + G[b, idx_k, co] )
// ---------------------------------------------------------------------------
__global__ void combine_kernel(const float* __restrict__ xq, int xq_bs,
                               const float* __restrict__ xs, int xs_bs,
                               const int* __restrict__ idx,
                               const float* __restrict__ G,
                               const float* __restrict__ base,
                               const float* __restrict__ bias,
                               const float* __restrict__ Wd, int cout,
                               float* __restrict__ out) {
    __shared__ float ds[KNN][3];
    __shared__ int   js[KNN];
    int b = blockIdx.y, n = blockIdx.x;
    long pn = (long)b * NN + n;
    if (threadIdx.x < KNN) {
        int j = idx[pn * KNN + threadIdx.x];
        js[threadIdx.x] = j;
        const float* sp = xs + (long)b * xs_bs + j * 3;
        const float* qp = xq + (long)b * xq_bs + n * 3;
        ds[threadIdx.x][0] = sp[0] - qp[0];
        ds[threadIdx.x][1] = sp[1] - qp[1];
        ds[threadIdx.x][2] = sp[2] - qp[2];
    }
    __syncthreads();

    int co = threadIdx.x;
    float wx = Wd[co], wy = Wd[cout + co], wz = Wd[2 * cout + co];
    float bv = base ? base[pn * cout + co] : bias[co];
    float acc = -1e30f;
#pragma unroll
    for (int k = 0; k < KNN; ++k) {
        float v = fmaf(ds[k][0], wx, bv);
        v = fmaf(ds[k][1], wy, v);
        v = fmaf(ds[k][2], wz, v);
        if (G) v += G[((long)b * NN + js[k]) * cout + co];
        acc = fmaxf(acc, v);
    }
    out[pn * cout + co] = acc;
}

// ---------------------------------------------------------------------------
// x_next = x_prev + h @ Wl + bl ; one wave per point
// ---------------------------------------------------------------------------
__global__ void motion_kernel(const float* __restrict__ h,
                              const float* __restrict__ Wl,
                              const float* __restrict__ bl,
                              const float* __restrict__ xprev, int xp_bs,
                              float* __restrict__ xnext, int xn_bs) {
    int lane = threadIdx.x & 63;
    int wave = threadIdx.x >> 6;
    int p = blockIdx.x * 4 + wave;
    int b = p / NN, n = p % NN;
    float hv = h[(long)p * 64 + lane];
    float m0 = hv * Wl[lane * 3 + 0];
    float m1 = hv * Wl[lane * 3 + 1];
    float m2 = hv * Wl[lane * 3 + 2];
#pragma unroll
    for (int off = 32; off >= 1; off >>= 1) {
        m0 += __shfl_down(m0, off, 64);
        m1 += __shfl_down(m1, off, 64);
        m2 += __shfl_down(m2, off, 64);
    }
    if (lane == 0) {
        const float* xp = xprev + (long)b * xp_bs + n * 3;
        float* xn = xnext + (long)b * xn_bs + n * 3;
        xn[0] = xp[0] + m0 + bl[0];
        xn[1] = xp[1] + m1 + bl[1];
        xn[2] = xp[2] + m2 + bl[2];
    }
}

extern "C" void kernel_launch(void* const* d_in, const int* in_sizes, int n_in,
                              void* d_out, int out_size, void* d_ws, size_t ws_size,
                              hipStream_t stream) {
    const float* frames = (const float*)d_in[0];
    const float* W1 = (const float*)d_in[1]; const float* b1 = (const float*)d_in[2];
    const float* W2 = (const float*)d_in[3]; const float* b2 = (const float*)d_in[4];
    const float* W3 = (const float*)d_in[5]; const float* b3 = (const float*)d_in[6];
    const float* Wm = (const float*)d_in[7]; const float* bm = (const float*)d_in[8];
    const float* Wl = (const float*)d_in[9]; const float* bl = (const float*)d_in[10];
    float* out = (float*)d_out;

    // workspace carve-up
    float* ws = (float*)d_ws;
    float* s1    = ws; ws += (size_t)BB * NN * 64;
    float* s2    = ws; ws += (size_t)BB * NN * 128;
    float* s3    = ws; ws += (size_t)BB * NN * 256;
    float* G1    = ws; ws += (size_t)BB * NN * 64;
    float* G2    = ws; ws += (size_t)BB * NN * 128;
    float* G3    = ws; ws += (size_t)BB * NN * 256;
    float* base2 = ws; ws += (size_t)BB * NN * 128;
    float* base3 = ws; ws += (size_t)BB * NN * 256;
    float* hbuf  = ws; ws += (size_t)BB * NN * 64;
    const long BNK = (long)BB * NN * KNN;
    int* ip = (int*)ws;
    int* idx1w = ip; ip += 7 * BNK;     // 7 warmup slots (steps 0..6)
    int* idx2w = ip; ip += 7 * BNK;
    int* idx3w = ip; ip += 7 * BNK;

    double ra = 4.0 + 1e-6, rb = 8.0 + 1e-6, rc = 12.0 + 1e-6;
    float r2a = (float)(ra * ra), r2b = (float)(rb * rb), r2c = (float)(rc * rc);

    const int FB = SEQ * NN * 3;
    const int OB = 6 * NN * 3;
    const int nb16 = BB * NN / 16;      // 512 blocks

    // all 7 warmup KNNs (depend only on frames) in one full-occupancy launch
    knn_kernel<<<dim3(NN / QB, BB, 7), 256, 0, stream>>>(
        frames, FB, nullptr, 0, idx1w, idx2w, idx3w, r2a, r2b, r2c, 1);

    for (int t = 0; t < SEQ; ++t) {
        const float* xq; int xq_bs;
        const float* xs; int xs_bs;
        if (t < 6)       { xq = frames + (long)t * NN * 3;        xq_bs = FB; }
        else if (t == 6) { xq = frames + 5L * NN * 3;             xq_bs = FB; }
        else             { xq = out + (long)(t - 7) * NN * 3;     xq_bs = OB; }
        if (t == 0)      { xs = xq;                               xs_bs = xq_bs; }
        else if (t <= 6) { xs = frames + (long)(t - 1) * NN * 3;  xs_bs = FB; }
        else if (t == 7) { xs = frames + 5L * NN * 3;             xs_bs = FB; }
        else             { xs = out + (long)(t - 8) * NN * 3;     xs_bs = OB; }

        bool first = (t == 0);
        int slot = (t <= 6) ? t : 0;    // t>=7 reuses slot 0 (long consumed)
        int* i1 = idx1w + slot * BNK;
        int* i2 = idx2w + slot * BNK;
        int* i3 = idx3w + slot * BNK;

        if (t >= 7)
            knn_kernel<<<dim3(NN / QB, BB, 1), 256, 0, stream>>>(
                xq, xq_bs, xs, xs_bs, i1, i2, i3, r2a, r2b, r2c, 0);

        // G1,G2,G3 fused (all depend only on previous step's s1,s2,s3)
        if (!first)
            multiG_kernel<<<3 * nb16, 256, 16 * 256 * 4, stream>>>(
                s1, W1 + 3 * 64, s2, W2 + 67 * 128, s3, W3 + 131 * 256,
                G1, G2, G3);

        // cell 1
        combine_kernel<<<dim3(NN, BB), 64, 0, stream>>>(
            xq, xq_bs, xs, xs_bs, i1, first ? nullptr : G1,
            nullptr, b1, W1, 64, s1);

        // cell 2
        gemm16_kernel<64, 128><<<nb16, 256, 16 * 64 * 4, stream>>>(
            s1, W2 + 3 * 128, b2, base2, 0);
        combine_kernel<<<dim3(NN, BB), 128, 0, stream>>>(
            xq, xq_bs, xs, xs_bs, i2, first ? nullptr : G2,
            base2, nullptr, W2, 128, s2);

        // cell 3
        gemm16_kernel<128, 256><<<nb16, 256, 16 * 128 * 4, stream>>>(
            s2, W3 + 3 * 256, b3, base3, 0);
        combine_kernel<<<dim3(NN, BB), 256, 0, stream>>>(
            xq, xq_bs, xs, xs_bs, i3, first ? nullptr : G3,
            base3, nullptr, W3, 256, s3);

        // prediction head
        if (t >= 6) {
            gemm16_kernel<256, 64><<<nb16, 256, 16 * 256 * 4, stream>>>(
                s3, Wm, bm, hbuf, 1);
            motion_kernel<<<BB * NN / 4, 256, 0, stream>>>(
                hbuf, Wl, bl, xq, xq_bs, out + (long)(t - 6) * NN * 3, OB);
        }
    }
}

// Round 4
// 1344.985 us; speedup vs baseline: 3.0111x; 1.0392x over previous
//
#include <hip/hip_runtime.h>
#include <math.h>

#define BB 16
#define NN 512
#define KNN 8
#define SEQ 12
#define TQ 8            // knn: threads per query
#define QB 32           // knn: queries per block (TQ*QB = 256 threads)
#define PB 16           // cells: points per block

// ---------------------------------------------------------------------------
// KNN (unchanged from round 3 — verified correct, conflict-free layout).
// warm=1: blockIdx.z = step t in 0..6, pointers derived from frames.
// ---------------------------------------------------------------------------
__global__ __launch_bounds__(256) void knn_kernel(
        const float* __restrict__ xq, int xq_bs,
        const float* __restrict__ xs, int xs_bs,
        int* __restrict__ idx1, int* __restrict__ idx2, int* __restrict__ idx3,
        float r2a, float r2b, float r2c, int warm) {
    __shared__ float s[NN * 3 + NN / 64];
    __shared__ float cd[QB][TQ][KNN + 1];
    __shared__ int   ci[QB][TQ][KNN + 1];
    int b = blockIdx.y;
    const float* xqp; const float* xsp; long iofs;
    if (warm) {
        int z = blockIdx.z;
        int qz = z < 5 ? z : 5;
        int sz = z - 1 < 0 ? 0 : z - 1;
        xqp = xq + (long)qz * NN * 3;
        xsp = xq + (long)sz * NN * 3;
        xs_bs = xq_bs;
        iofs = (long)z * BB * NN * KNN;
    } else {
        xqp = xq; xsp = xs; iofs = 0;
    }

    for (int j = threadIdx.x; j < NN; j += 256) {
        const float* p = xsp + (long)b * xs_bs + j * 3;
        int o = 3 * j + (j >> 6);
        s[o + 0] = p[0]; s[o + 1] = p[1]; s[o + 2] = p[2];
    }
    __syncthreads();

    int qi  = threadIdx.x / TQ;
    int sub = threadIdx.x % TQ;
    int n = blockIdx.x * QB + qi;
    const float* q = xqp + (long)b * xq_bs + n * 3;
    float qx = q[0], qy = q[1], qz2 = q[2];

    float bd[KNN];
    int   bi[KNN];
#pragma unroll
    for (int k = 0; k < KNN; ++k) { bd[k] = 1e30f; bi[k] = 0; }

    int j0 = sub * (NN / TQ);
    int sbase = 3 * j0 + sub;
#pragma unroll 4
    for (int jj = 0; jj < NN / TQ; ++jj) {
        float dx = s[sbase + 3 * jj + 0] - qx;
        float dy = s[sbase + 3 * jj + 1] - qy;
        float dz = s[sbase + 3 * jj + 2] - qz2;
        float d2 = fmaf(dx, dx, fmaf(dy, dy, dz * dz));
        if (d2 < bd[KNN - 1]) {
            bd[KNN - 1] = d2; bi[KNN - 1] = j0 + jj;
#pragma unroll
            for (int k = KNN - 1; k >= 1; --k) {
                if (bd[k] < bd[k - 1]) {
                    float td = bd[k]; bd[k] = bd[k - 1]; bd[k - 1] = td;
                    int   ti = bi[k]; bi[k] = bi[k - 1]; bi[k - 1] = ti;
                }
            }
        }
    }

#pragma unroll
    for (int k = 0; k < KNN; ++k) { cd[qi][sub][k] = bd[k]; ci[qi][sub][k] = bi[k]; }
    cd[qi][sub][KNN] = 1e30f; ci[qi][sub][KNN] = 0x7fffffff;
    __syncthreads();

    for (int stride = TQ / 2; stride >= 1; stride >>= 1) {
        if (sub < stride) {
            float rd[KNN]; int ri[KNN];
            int ia = 0, ib = 0;
#pragma unroll
            for (int k = 0; k < KNN; ++k) {
                float da = cd[qi][sub][ia], db = cd[qi][sub + stride][ib];
                int   ja = ci[qi][sub][ia], jb = ci[qi][sub + stride][ib];
                bool ta = (da < db) || (da == db && ja < jb);
                rd[k] = ta ? da : db; ri[k] = ta ? ja : jb;
                ia += ta ? 1 : 0; ib += ta ? 0 : 1;
            }
#pragma unroll
            for (int k = 0; k < KNN; ++k) { cd[qi][sub][k] = rd[k]; ci[qi][sub][k] = ri[k]; }
        }
        __syncthreads();
    }

    if (sub == 0) {
        long base = iofs + ((long)(b * NN + n)) * KNN;
        int i0 = ci[qi][0][0];
#pragma unroll
        for (int k = 0; k < KNN; ++k) {
            float d = cd[qi][0][k]; int j = ci[qi][0][k];
            idx1[base + k] = (d <= r2a) ? j : i0;
            idx2[base + k] = (d <= r2b) ? j : i0;
            idx3[base + k] = (d <= r2c) ? j : i0;
        }
    }
}

// ---------------------------------------------------------------------------
// Fully fused per-step cell pipeline. 16 points per block (all in one batch),
// 256 threads. Everything per-point after knn: combine1 -> G1next -> base2 ->
// combine2 (in-place, same thread mapping) -> G2next -> base3 -> combine3
// (in-place) -> G3next -> head. G double-buffered across steps by parity.
// ---------------------------------------------------------------------------
template<bool FIRST>
__global__ __launch_bounds__(256) void cells_kernel(
        const float* __restrict__ xq, int xq_bs,
        const float* __restrict__ xs, int xs_bs,
        const int* __restrict__ i1, const int* __restrict__ i2,
        const int* __restrict__ i3,
        const float* __restrict__ G1p, const float* __restrict__ G2p,
        const float* __restrict__ G3p,
        float* __restrict__ G1n, float* __restrict__ G2n,
        float* __restrict__ G3n,
        const float* __restrict__ W1, const float* __restrict__ b1,
        const float* __restrict__ W2, const float* __restrict__ b2,
        const float* __restrict__ W3, const float* __restrict__ b3,
        const float* __restrict__ Wm, const float* __restrict__ bm,
        const float* __restrict__ Wl, const float* __restrict__ bl,
        float* __restrict__ xnext, int xn_bs, int do_head, int do_g) {
    __shared__ float s1s[PB][64];
    __shared__ float s2s[PB][128];
    __shared__ float s3b[PB][256];
    __shared__ float hs[PB][64];
    __shared__ float dsp[3][PB][KNN][3];
    __shared__ int   jss[3][PB][KNN];

    const int tid = threadIdx.x;
    const int blk = blockIdx.x;          // 0..511
    const int b   = blk >> 5;            // 32 blocks per batch
    const int n0  = (blk & 31) << 4;
    const long row0 = (long)b * NN + n0;

    // P0: neighbor indices + displacements for all 3 radii
    for (int t = tid; t < 3 * PB * KNN; t += 256) {
        int r = t >> 7, rem = t & 127, p = rem >> 3, k = rem & 7;
        const int* ix = (r == 0) ? i1 : ((r == 1) ? i2 : i3);
        int j = ix[(row0 + p) * KNN + k];
        jss[r][p][k] = j;
        const float* sp = xs + (long)b * xs_bs + j * 3;
        const float* qp = xq + (long)b * xq_bs + (n0 + p) * 3;
        dsp[r][p][k][0] = sp[0] - qp[0];
        dsp[r][p][k][1] = sp[1] - qp[1];
        dsp[r][p][k][2] = sp[2] - qp[2];
    }
    __syncthreads();

    // P1: cell1 combine -> s1s
    {
        int co = tid & 63, q = tid >> 6;
        float wx = W1[co], wy = W1[64 + co], wz = W1[128 + co];
        float bz = b1[co];
#pragma unroll
        for (int r = 0; r < 4; ++r) {
            int p = q * 4 + r;
            float acc = -1e30f;
#pragma unroll
            for (int k = 0; k < KNN; ++k) {
                float v = fmaf(dsp[0][p][k][0], wx, bz);
                v = fmaf(dsp[0][p][k][1], wy, v);
                v = fmaf(dsp[0][p][k][2], wz, v);
                if (!FIRST) v += G1p[((long)b * NN + jss[0][p][k]) * 64 + co];
                acc = fmaxf(acc, v);
            }
            s1s[p][co] = acc;
        }
    }
    __syncthreads();

    // P1b: G1 for next step = s1s @ W1n
    if (do_g) {
        int co = tid & 63, q = tid >> 6;
        const float* W1n = W1 + 3 * 64;
        float acc[4] = {0.f, 0.f, 0.f, 0.f};
        for (int c = 0; c < 64; ++c) {
            float w = W1n[c * 64 + co];
#pragma unroll
            for (int r = 0; r < 4; ++r)
                acc[r] = fmaf(s1s[q * 4 + r][c], w, acc[r]);
        }
#pragma unroll
        for (int r = 0; r < 4; ++r)
            G1n[(row0 + q * 4 + r) * 64 + co] = acc[r];
    }

    // P2: base2 = s1s @ W2f + b2 -> s2s
    {
        int co = tid & 127, g = tid >> 7;
        const float* W2f = W2 + 3 * 128;
        float bz = b2[co];
        float acc[8];
#pragma unroll
        for (int r = 0; r < 8; ++r) acc[r] = bz;
        for (int c = 0; c < 64; ++c) {
            float w = W2f[c * 128 + co];
#pragma unroll
            for (int r = 0; r < 8; ++r)
                acc[r] = fmaf(s1s[g * 8 + r][c], w, acc[r]);
        }
#pragma unroll
        for (int r = 0; r < 8; ++r) s2s[g * 8 + r][co] = acc[r];
    }
    // P3: cell2 combine, in place (same thread<->cell mapping as P2: no sync)
    {
        int co = tid & 127, g = tid >> 7;
        float wx = W2[co], wy = W2[128 + co], wz = W2[256 + co];
#pragma unroll
        for (int r = 0; r < 8; ++r) {
            int p = g * 8 + r;
            float bv = s2s[p][co];
            float acc = -1e30f;
#pragma unroll
            for (int k = 0; k < KNN; ++k) {
                float v = fmaf(dsp[1][p][k][0], wx, bv);
                v = fmaf(dsp[1][p][k][1], wy, v);
                v = fmaf(dsp[1][p][k][2], wz, v);
                if (!FIRST) v += G2p[((long)b * NN + jss[1][p][k]) * 128 + co];
                acc = fmaxf(acc, v);
            }
            s2s[p][co] = acc;
        }
    }
    __syncthreads();

    // P3b: G2 next = s2s @ W2n
    if (do_g) {
        int co = tid & 127, g = tid >> 7;
        const float* W2n = W2 + 67 * 128;
        float acc[8];
#pragma unroll
        for (int r = 0; r < 8; ++r) acc[r] = 0.f;
        for (int c = 0; c < 128; ++c) {
            float w = W2n[c * 128 + co];
#pragma unroll
            for (int r = 0; r < 8; ++r)
                acc[r] = fmaf(s2s[g * 8 + r][c], w, acc[r]);
        }
#pragma unroll
        for (int r = 0; r < 8; ++r)
            G2n[(row0 + g * 8 + r) * 128 + co] = acc[r];
    }

    // P4: base3 = s2s @ W3f + b3 -> s3b
    {
        int co = tid;
        const float* W3f = W3 + 3 * 256;
        float bz = b3[co];
        float acc[16];
#pragma unroll
        for (int r = 0; r < 16; ++r) acc[r] = bz;
#pragma unroll 2
        for (int c = 0; c < 128; ++c) {
            float w = W3f[c * 256 + co];
#pragma unroll
            for (int r = 0; r < 16; ++r)
                acc[r] = fmaf(s2s[r][c], w, acc[r]);
        }
#pragma unroll
        for (int r = 0; r < 16; ++r) s3b[r][co] = acc[r];
    }
    // P5: cell3 combine, in place (same mapping as P4: no sync)
    {
        int co = tid;
        float wx = W3[co], wy = W3[256 + co], wz = W3[512 + co];
#pragma unroll
        for (int p = 0; p < 16; ++p) {
            float bv = s3b[p][co];
            float acc = -1e30f;
#pragma unroll
            for (int k = 0; k < KNN; ++k) {
                float v = fmaf(dsp[2][p][k][0], wx, bv);
                v = fmaf(dsp[2][p][k][1], wy, v);
                v = fmaf(dsp[2][p][k][2], wz, v);
                if (!FIRST) v += G3p[((long)b * NN + jss[2][p][k]) * 256 + co];
                acc = fmaxf(acc, v);
            }
            s3b[p][co] = acc;
        }
    }
    __syncthreads();

    // P5b: G3 next = s3b @ W3n
    if (do_g) {
        int co = tid;
        const float* W3n = W3 + 131 * 256;
        float acc[16];
#pragma unroll
        for (int r = 0; r < 16; ++r) acc[r] = 0.f;
#pragma unroll 2
        for (int c = 0; c < 256; ++c) {
            float w = W3n[c * 256 + co];
#pragma unroll
            for (int r = 0; r < 16; ++r)
                acc[r] = fmaf(s3b[r][c], w, acc[r]);
        }
#pragma unroll
        for (int r = 0; r < 16; ++r)
            G3n[(row0 + r) * 256 + co] = acc[r];
    }

    // P6: prediction head
    if (do_head) {
        {
            int co = tid & 63, q = tid >> 6;
            float bz = bm[co];
            float acc[4];
#pragma unroll
            for (int r = 0; r < 4; ++r) acc[r] = bz;
#pragma unroll 2
            for (int c = 0; c < 256; ++c) {
                float w = Wm[c * 64 + co];
#pragma unroll
                for (int r = 0; r < 4; ++r)
                    acc[r] = fmaf(s3b[q * 4 + r][c], w, acc[r]);
            }
#pragma unroll
            for (int r = 0; r < 4; ++r)
                hs[q * 4 + r][co] = fmaxf(acc[r], 0.f);
        }
        __syncthreads();
        if (tid < PB * 3) {
            int p = tid / 3, d = tid % 3;
            float m = bl[d];
            for (int c = 0; c < 64; ++c)
                m = fmaf(hs[p][c], Wl[c * 3 + d], m);
            const float* qp = xq + (long)b * xq_bs + (n0 + p) * 3;
            xnext[(long)b * xn_bs + (n0 + p) * 3 + d] = qp[d] + m;
        }
    }
}

extern "C" void kernel_launch(void* const* d_in, const int* in_sizes, int n_in,
                              void* d_out, int out_size, void* d_ws, size_t ws_size,
                              hipStream_t stream) {
    const float* frames = (const float*)d_in[0];
    const float* W1 = (const float*)d_in[1]; const float* b1 = (const float*)d_in[2];
    const float* W2 = (const float*)d_in[3]; const float* b2 = (const float*)d_in[4];
    const float* W3 = (const float*)d_in[5]; const float* b3 = (const float*)d_in[6];
    const float* Wm = (const float*)d_in[7]; const float* bm = (const float*)d_in[8];
    const float* Wl = (const float*)d_in[9]; const float* bl = (const float*)d_in[10];
    float* out = (float*)d_out;

    // workspace: double-buffered G (by step parity) + warmup index slots
    float* ws = (float*)d_ws;
    float* G1s[2]; float* G2s[2]; float* G3s[2];
    for (int p = 0; p < 2; ++p) {
        G1s[p] = ws; ws += (size_t)BB * NN * 64;
        G2s[p] = ws; ws += (size_t)BB * NN * 128;
        G3s[p] = ws; ws += (size_t)BB * NN * 256;
    }
    const long BNK = (long)BB * NN * KNN;
    int* ip = (int*)ws;
    int* idx1w = ip; ip += 7 * BNK;
    int* idx2w = ip; ip += 7 * BNK;
    int* idx3w = ip; ip += 7 * BNK;

    double ra = 4.0 + 1e-6, rb = 8.0 + 1e-6, rc = 12.0 + 1e-6;
    float r2a = (float)(ra * ra), r2b = (float)(rb * rb), r2c = (float)(rc * rc);

    const int FB = SEQ * NN * 3;
    const int OB = 6 * NN * 3;

    // all 7 warmup KNNs in one full-occupancy launch
    knn_kernel<<<dim3(NN / QB, BB, 7), 256, 0, stream>>>(
        frames, FB, nullptr, 0, idx1w, idx2w, idx3w, r2a, r2b, r2c, 1);

    for (int t = 0; t < SEQ; ++t) {
        const float* xq; int xq_bs;
        const float* xs; int xs_bs;
        if (t < 6)       { xq = frames + (long)t * NN * 3;        xq_bs = FB; }
        else if (t == 6) { xq = frames + 5L * NN * 3;             xq_bs = FB; }
        else             { xq = out + (long)(t - 7) * NN * 3;     xq_bs = OB; }
        if (t == 0)      { xs = xq;                               xs_bs = xq_bs; }
        else if (t <= 6) { xs = frames + (long)(t - 1) * NN * 3;  xs_bs = FB; }
        else if (t == 7) { xs = frames + 5L * NN * 3;             xs_bs = FB; }
        else             { xs = out + (long)(t - 8) * NN * 3;     xs_bs = OB; }

        int slot = (t <= 6) ? t : 0;
        int* i1 = idx1w + slot * BNK;
        int* i2 = idx2w + slot * BNK;
        int* i3 = idx3w + slot * BNK;

        if (t >= 7)
            knn_kernel<<<dim3(NN / QB, BB, 1), 256, 0, stream>>>(
                xq, xq_bs, xs, xs_bs, i1, i2, i3, r2a, r2b, r2c, 0);

        int rd = t & 1, wr = (t + 1) & 1;
        int do_head = (t >= 6);
        int do_g = (t < SEQ - 1);
        float* xnext = do_head ? out + (long)(t - 6) * NN * 3 : nullptr;

        if (t == 0)
            cells_kernel<true><<<BB * NN / PB, 256, 0, stream>>>(
                xq, xq_bs, xs, xs_bs, i1, i2, i3,
                G1s[rd], G2s[rd], G3s[rd], G1s[wr], G2s[wr], G3s[wr],
                W1, b1, W2, b2, W3, b3, Wm, bm, Wl, bl,
                xnext, OB, do_head, do_g);
        else
            cells_kernel<false><<<BB * NN / PB, 256, 0, stream>>>(
                xq, xq_bs, xs, xs_bs, i1, i2, i3,
                G1s[rd], G2s[rd], G3s[rd], G1s[wr], G2s[wr], G3s[wr],
                W1, b1, W2, b2, W3, b3, Wm, bm, Wl, bl,
                xnext, OB, do_head, do_g);
    }
}

// Round 5
// 1187.125 us; speedup vs baseline: 3.4115x; 1.1330x over previous
//
#include <hip/hip_runtime.h>
#include <math.h>

#define BB 16
#define NN 512
#define KNN 8
#define SEQ 12
#define TQ 8            // knn: threads per query
#define QB 32           // knn: queries per block (TQ*QB = 256 threads)
#define PB 16           // cells: points per block

// ---------------------------------------------------------------------------
// KNN (unchanged — verified correct, conflict-free layout).
// ---------------------------------------------------------------------------
__global__ __launch_bounds__(256) void knn_kernel(
        const float* __restrict__ xq, int xq_bs,
        const float* __restrict__ xs, int xs_bs,
        int* __restrict__ idx1, int* __restrict__ idx2, int* __restrict__ idx3,
        float r2a, float r2b, float r2c, int warm) {
    __shared__ float s[NN * 3 + NN / 64];
    __shared__ float cd[QB][TQ][KNN + 1];
    __shared__ int   ci[QB][TQ][KNN + 1];
    int b = blockIdx.y;
    const float* xqp; const float* xsp; long iofs;
    if (warm) {
        int z = blockIdx.z;
        int qz = z < 5 ? z : 5;
        int sz = z - 1 < 0 ? 0 : z - 1;
        xqp = xq + (long)qz * NN * 3;
        xsp = xq + (long)sz * NN * 3;
        xs_bs = xq_bs;
        iofs = (long)z * BB * NN * KNN;
    } else {
        xqp = xq; xsp = xs; iofs = 0;
    }

    for (int j = threadIdx.x; j < NN; j += 256) {
        const float* p = xsp + (long)b * xs_bs + j * 3;
        int o = 3 * j + (j >> 6);
        s[o + 0] = p[0]; s[o + 1] = p[1]; s[o + 2] = p[2];
    }
    __syncthreads();

    int qi  = threadIdx.x / TQ;
    int sub = threadIdx.x % TQ;
    int n = blockIdx.x * QB + qi;
    const float* q = xqp + (long)b * xq_bs + n * 3;
    float qx = q[0], qy = q[1], qz2 = q[2];

    float bd[KNN];
    int   bi[KNN];
#pragma unroll
    for (int k = 0; k < KNN; ++k) { bd[k] = 1e30f; bi[k] = 0; }

    int j0 = sub * (NN / TQ);
    int sbase = 3 * j0 + sub;
#pragma unroll 4
    for (int jj = 0; jj < NN / TQ; ++jj) {
        float dx = s[sbase + 3 * jj + 0] - qx;
        float dy = s[sbase + 3 * jj + 1] - qy;
        float dz = s[sbase + 3 * jj + 2] - qz2;
        float d2 = fmaf(dx, dx, fmaf(dy, dy, dz * dz));
        if (d2 < bd[KNN - 1]) {
            bd[KNN - 1] = d2; bi[KNN - 1] = j0 + jj;
#pragma unroll
            for (int k = KNN - 1; k >= 1; --k) {
                if (bd[k] < bd[k - 1]) {
                    float td = bd[k]; bd[k] = bd[k - 1]; bd[k - 1] = td;
                    int   ti = bi[k]; bi[k] = bi[k - 1]; bi[k - 1] = ti;
                }
            }
        }
    }

#pragma unroll
    for (int k = 0; k < KNN; ++k) { cd[qi][sub][k] = bd[k]; ci[qi][sub][k] = bi[k]; }
    cd[qi][sub][KNN] = 1e30f; ci[qi][sub][KNN] = 0x7fffffff;
    __syncthreads();

    for (int stride = TQ / 2; stride >= 1; stride >>= 1) {
        if (sub < stride) {
            float rd[KNN]; int ri[KNN];
            int ia = 0, ib = 0;
#pragma unroll
            for (int k = 0; k < KNN; ++k) {
                float da = cd[qi][sub][ia], db = cd[qi][sub + stride][ib];
                int   ja = ci[qi][sub][ia], jb = ci[qi][sub + stride][ib];
                bool ta = (da < db) || (da == db && ja < jb);
                rd[k] = ta ? da : db; ri[k] = ta ? ja : jb;
                ia += ta ? 1 : 0; ib += ta ? 0 : 1;
            }
#pragma unroll
            for (int k = 0; k < KNN; ++k) { cd[qi][sub][k] = rd[k]; ci[qi][sub][k] = ri[k]; }
        }
        __syncthreads();
    }

    if (sub == 0) {
        long base = iofs + ((long)(b * NN + n)) * KNN;
        int i0 = ci[qi][0][0];
#pragma unroll
        for (int k = 0; k < KNN; ++k) {
            float d = cd[qi][0][k]; int j = ci[qi][0][k];
            idx1[base + k] = (d <= r2a) ? j : i0;
            idx2[base + k] = (d <= r2b) ? j : i0;
            idx3[base + k] = (d <= r2c) ? j : i0;
        }
    }
}

// ---------------------------------------------------------------------------
// Fused per-step cell pipeline, 512 threads, 16 points/block, float4 weight
// tiles. Phases: P0 gather disp/idx | P1 combine1 | P1b G1n, P2+P3 base2+
// combine2 (in regs) | P3b G2n, P4+P5 base3+combine3 (in regs) | P5b G3n,
// P6 head. G double-buffered across steps by parity.
// ---------------------------------------------------------------------------
template<bool FIRST>
__global__ __launch_bounds__(512) void cells_kernel(
        const float* __restrict__ xq, int xq_bs,
        const float* __restrict__ xs, int xs_bs,
        const int* __restrict__ i1, const int* __restrict__ i2,
        const int* __restrict__ i3,
        const float* __restrict__ G1p, const float* __restrict__ G2p,
        const float* __restrict__ G3p,
        float* __restrict__ G1n, float* __restrict__ G2n,
        float* __restrict__ G3n,
        const float* __restrict__ W1, const float* __restrict__ b1,
        const float* __restrict__ W2, const float* __restrict__ b2,
        const float* __restrict__ W3, const float* __restrict__ b3,
        const float* __restrict__ Wm, const float* __restrict__ bm,
        const float* __restrict__ Wl, const float* __restrict__ bl,
        float* __restrict__ xnext, int xn_bs, int do_head, int do_g) {
    __shared__ float s1s[PB][64];
    __shared__ float s2s[PB][128];
    __shared__ float s3b[PB][256];
    __shared__ float hs[PB][64];
    __shared__ float dsp[3][PB][KNN][3];
    __shared__ int   jss[3][PB][KNN];

    const int tid = threadIdx.x;
    const int blk = blockIdx.x;          // 0..511
    const int b   = blk >> 5;
    const int n0  = (blk & 31) << 4;
    const long row0 = (long)b * NN + n0;
    const long bN = (long)b * NN;

    // P0: neighbor indices + displacements for all 3 radii
    for (int t = tid; t < 3 * PB * KNN; t += 512) {
        int r = t >> 7, rem = t & 127, p = rem >> 3, k = rem & 7;
        const int* ix = (r == 0) ? i1 : ((r == 1) ? i2 : i3);
        int j = ix[(row0 + p) * KNN + k];
        jss[r][p][k] = j;
        const float* sp = xs + (long)b * xs_bs + j * 3;
        const float* qp = xq + (long)b * xq_bs + (n0 + p) * 3;
        dsp[r][p][k][0] = sp[0] - qp[0];
        dsp[r][p][k][1] = sp[1] - qp[1];
        dsp[r][p][k][2] = sp[2] - qp[2];
    }
    __syncthreads();

    // P1: cell1 combine -> s1s  (co scalar; gather rows are 256B coalesced)
    {
        int co = tid & 63, q = tid >> 6;       // q: 0..7, rows 2q,2q+1
        float wx = W1[co], wy = W1[64 + co], wz = W1[128 + co];
        float bz = b1[co];
#pragma unroll
        for (int r = 0; r < 2; ++r) {
            int p = q * 2 + r;
            float acc = -1e30f;
#pragma unroll
            for (int k = 0; k < KNN; ++k) {
                float v = fmaf(dsp[0][p][k][0], wx, bz);
                v = fmaf(dsp[0][p][k][1], wy, v);
                v = fmaf(dsp[0][p][k][2], wz, v);
                if (!FIRST) v += G1p[(bN + jss[0][p][k]) * 64 + co];
                acc = fmaxf(acc, v);
            }
            s1s[p][co] = acc;
        }
    }
    __syncthreads();

    // P1b: G1 next = s1s @ W1n (small, scalar)
    if (do_g) {
        int co = tid & 63, q = tid >> 6;
        const float* W1n = W1 + 3 * 64;
        float a0 = 0.f, a1 = 0.f;
#pragma unroll 4
        for (int c = 0; c < 64; ++c) {
            float w = W1n[c * 64 + co];
            a0 = fmaf(s1s[2 * q][c], w, a0);
            a1 = fmaf(s1s[2 * q + 1][c], w, a1);
        }
        G1n[(row0 + 2 * q) * 64 + co] = a0;
        G1n[(row0 + 2 * q + 1) * 64 + co] = a1;
    }

    // P2+P3: base2 then combine2 kept in registers; thread owns row g, cols
    // 4*c4..4*c4+3 (float4 weight loads, broadcast LDS activation reads)
    {
        int c4 = tid & 31, g = tid >> 5;       // g: 0..15 (the point)
        const float4* W2f4 = (const float4*)(W2 + 3 * 128);
        float4 acc = ((const float4*)b2)[c4];
#pragma unroll 4
        for (int c = 0; c < 64; ++c) {
            float4 w = W2f4[c * 32 + c4];
            float x = s1s[g][c];
            acc.x = fmaf(x, w.x, acc.x); acc.y = fmaf(x, w.y, acc.y);
            acc.z = fmaf(x, w.z, acc.z); acc.w = fmaf(x, w.w, acc.w);
        }
        float4 wx = ((const float4*)W2)[c4];
        float4 wy = ((const float4*)(W2 + 128))[c4];
        float4 wz = ((const float4*)(W2 + 256))[c4];
        float4 m = make_float4(-1e30f, -1e30f, -1e30f, -1e30f);
#pragma unroll
        for (int k = 0; k < KNN; ++k) {
            float dx = dsp[1][g][k][0], dy = dsp[1][g][k][1], dz = dsp[1][g][k][2];
            float4 v;
            v.x = fmaf(dz, wz.x, fmaf(dy, wy.x, fmaf(dx, wx.x, acc.x)));
            v.y = fmaf(dz, wz.y, fmaf(dy, wy.y, fmaf(dx, wx.y, acc.y)));
            v.z = fmaf(dz, wz.z, fmaf(dy, wy.z, fmaf(dx, wx.z, acc.z)));
            v.w = fmaf(dz, wz.w, fmaf(dy, wy.w, fmaf(dx, wx.w, acc.w)));
            if (!FIRST) {
                float4 g4 = ((const float4*)G2p)[(bN + jss[1][g][k]) * 32 + c4];
                v.x += g4.x; v.y += g4.y; v.z += g4.z; v.w += g4.w;
            }
            m.x = fmaxf(m.x, v.x); m.y = fmaxf(m.y, v.y);
            m.z = fmaxf(m.z, v.z); m.w = fmaxf(m.w, v.w);
        }
        *(float4*)&s2s[g][c4 * 4] = m;
    }
    __syncthreads();

    // P3b: G2 next = s2s @ W2n
    if (do_g) {
        int c4 = tid & 31, g = tid >> 5;
        const float4* W2n4 = (const float4*)(W2 + 67 * 128);
        float4 acc = make_float4(0.f, 0.f, 0.f, 0.f);
#pragma unroll 4
        for (int c = 0; c < 128; ++c) {
            float4 w = W2n4[c * 32 + c4];
            float x = s2s[g][c];
            acc.x = fmaf(x, w.x, acc.x); acc.y = fmaf(x, w.y, acc.y);
            acc.z = fmaf(x, w.z, acc.z); acc.w = fmaf(x, w.w, acc.w);
        }
        *(float4*)&G2n[(row0 + g) * 128 + c4 * 4] = acc;
    }

    // P4+P5: base3 then combine3 in registers; thread owns rows 2g,2g+1,
    // cols 4*c4..4*c4+3
    {
        int c4 = tid & 63, g = tid >> 6;       // g: 0..7
        const float4* W3f4 = (const float4*)(W3 + 3 * 256);
        float4 bz4 = ((const float4*)b3)[c4];
        float4 a0 = bz4, a1 = bz4;
#pragma unroll 4
        for (int c = 0; c < 128; ++c) {
            float4 w = W3f4[c * 64 + c4];
            float x0 = s2s[2 * g][c], x1 = s2s[2 * g + 1][c];
            a0.x = fmaf(x0, w.x, a0.x); a0.y = fmaf(x0, w.y, a0.y);
            a0.z = fmaf(x0, w.z, a0.z); a0.w = fmaf(x0, w.w, a0.w);
            a1.x = fmaf(x1, w.x, a1.x); a1.y = fmaf(x1, w.y, a1.y);
            a1.z = fmaf(x1, w.z, a1.z); a1.w = fmaf(x1, w.w, a1.w);
        }
        float4 wx = ((const float4*)W3)[c4];
        float4 wy = ((const float4*)(W3 + 256))[c4];
        float4 wz = ((const float4*)(W3 + 512))[c4];
#pragma unroll
        for (int r = 0; r < 2; ++r) {
            int p = 2 * g + r;
            float4 bse = r ? a1 : a0;
            float4 m = make_float4(-1e30f, -1e30f, -1e30f, -1e30f);
#pragma unroll
            for (int k = 0; k < KNN; ++k) {
                float dx = dsp[2][p][k][0], dy = dsp[2][p][k][1], dz = dsp[2][p][k][2];
                float4 v;
                v.x = fmaf(dz, wz.x, fmaf(dy, wy.x, fmaf(dx, wx.x, bse.x)));
                v.y = fmaf(dz, wz.y, fmaf(dy, wy.y, fmaf(dx, wx.y, bse.y)));
                v.z = fmaf(dz, wz.z, fmaf(dy, wy.z, fmaf(dx, wx.z, bse.z)));
                v.w = fmaf(dz, wz.w, fmaf(dy, wy.w, fmaf(dx, wx.w, bse.w)));
                if (!FIRST) {
                    float4 g4 = ((const float4*)G3p)[(bN + jss[2][p][k]) * 64 + c4];
                    v.x += g4.x; v.y += g4.y; v.z += g4.z; v.w += g4.w;
                }
                m.x = fmaxf(m.x, v.x); m.y = fmaxf(m.y, v.y);
                m.z = fmaxf(m.z, v.z); m.w = fmaxf(m.w, v.w);
            }
            *(float4*)&s3b[p][c4 * 4] = m;
        }
    }
    __syncthreads();

    // P5b: G3 next = s3b @ W3n
    if (do_g) {
        int c4 = tid & 63, g = tid >> 6;
        const float4* W3n4 = (const float4*)(W3 + 131 * 256);
        float4 a0 = make_float4(0.f, 0.f, 0.f, 0.f);
        float4 a1 = a0;
#pragma unroll 4
        for (int c = 0; c < 256; ++c) {
            float4 w = W3n4[c * 64 + c4];
            float x0 = s3b[2 * g][c], x1 = s3b[2 * g + 1][c];
            a0.x = fmaf(x0, w.x, a0.x); a0.y = fmaf(x0, w.y, a0.y);
            a0.z = fmaf(x0, w.z, a0.z); a0.w = fmaf(x0, w.w, a0.w);
            a1.x = fmaf(x1, w.x, a1.x); a1.y = fmaf(x1, w.y, a1.y);
            a1.z = fmaf(x1, w.z, a1.z); a1.w = fmaf(x1, w.w, a1.w);
        }
        *(float4*)&G3n[(row0 + 2 * g) * 256 + c4 * 4] = a0;
        *(float4*)&G3n[(row0 + 2 * g + 1) * 256 + c4 * 4] = a1;
    }

    // P6: prediction head
    if (do_head) {
        {
            int co = tid & 63, q = tid >> 6;   // rows 2q,2q+1
            float a0 = bm[co], a1 = a0;
#pragma unroll 4
            for (int c = 0; c < 256; ++c) {
                float w = Wm[c * 64 + co];
                a0 = fmaf(s3b[2 * q][c], w, a0);
                a1 = fmaf(s3b[2 * q + 1][c], w, a1);
            }
            hs[2 * q][co] = fmaxf(a0, 0.f);
            hs[2 * q + 1][co] = fmaxf(a1, 0.f);
        }
        __syncthreads();
        if (tid < PB * 3) {
            int p = tid / 3, d = tid % 3;
            float m = bl[d];
#pragma unroll 4
            for (int c = 0; c < 64; ++c)
                m = fmaf(hs[p][c], Wl[c * 3 + d], m);
            const float* qp = xq + (long)b * xq_bs + (n0 + p) * 3;
            xnext[(long)b * xn_bs + (n0 + p) * 3 + d] = qp[d] + m;
        }
    }
}

extern "C" void kernel_launch(void* const* d_in, const int* in_sizes, int n_in,
                              void* d_out, int out_size, void* d_ws, size_t ws_size,
                              hipStream_t stream) {
    const float* frames = (const float*)d_in[0];
    const float* W1 = (const float*)d_in[1]; const float* b1 = (const float*)d_in[2];
    const float* W2 = (const float*)d_in[3]; const float* b2 = (const float*)d_in[4];
    const float* W3 = (const float*)d_in[5]; const float* b3 = (const float*)d_in[6];
    const float* Wm = (const float*)d_in[7]; const float* bm = (const float*)d_in[8];
    const float* Wl = (const float*)d_in[9]; const float* bl = (const float*)d_in[10];
    float* out = (float*)d_out;

    float* ws = (float*)d_ws;
    float* G1s[2]; float* G2s[2]; float* G3s[2];
    for (int p = 0; p < 2; ++p) {
        G1s[p] = ws; ws += (size_t)BB * NN * 64;
        G2s[p] = ws; ws += (size_t)BB * NN * 128;
        G3s[p] = ws; ws += (size_t)BB * NN * 256;
    }
    const long BNK = (long)BB * NN * KNN;
    int* ip = (int*)ws;
    int* idx1w = ip; ip += 7 * BNK;
    int* idx2w = ip; ip += 7 * BNK;
    int* idx3w = ip; ip += 7 * BNK;

    double ra = 4.0 + 1e-6, rb = 8.0 + 1e-6, rc = 12.0 + 1e-6;
    float r2a = (float)(ra * ra), r2b = (float)(rb * rb), r2c = (float)(rc * rc);

    const int FB = SEQ * NN * 3;
    const int OB = 6 * NN * 3;

    knn_kernel<<<dim3(NN / QB, BB, 7), 256, 0, stream>>>(
        frames, FB, nullptr, 0, idx1w, idx2w, idx3w, r2a, r2b, r2c, 1);

    for (int t = 0; t < SEQ; ++t) {
        const float* xq; int xq_bs;
        const float* xs; int xs_bs;
        if (t < 6)       { xq = frames + (long)t * NN * 3;        xq_bs = FB; }
        else if (t == 6) { xq = frames + 5L * NN * 3;             xq_bs = FB; }
        else             { xq = out + (long)(t - 7) * NN * 3;     xq_bs = OB; }
        if (t == 0)      { xs = xq;                               xs_bs = xq_bs; }
        else if (t <= 6) { xs = frames + (long)(t - 1) * NN * 3;  xs_bs = FB; }
        else if (t == 7) { xs = frames + 5L * NN * 3;             xs_bs = FB; }
        else             { xs = out + (long)(t - 8) * NN * 3;     xs_bs = OB; }

        int slot = (t <= 6) ? t : 0;
        int* i1 = idx1w + slot * BNK;
        int* i2 = idx2w + slot * BNK;
        int* i3 = idx3w + slot * BNK;

        if (t >= 7)
            knn_kernel<<<dim3(NN / QB, BB, 1), 256, 0, stream>>>(
                xq, xq_bs, xs, xs_bs, i1, i2, i3, r2a, r2b, r2c, 0);

        int rd = t & 1, wr = (t + 1) & 1;
        int do_head = (t >= 6);
        int do_g = (t < SEQ - 1);
        float* xnext = do_head ? out + (long)(t - 6) * NN * 3 : nullptr;

        if (t == 0)
            cells_kernel<true><<<BB * NN / PB, 512, 0, stream>>>(
                xq, xq_bs, xs, xs_bs, i1, i2, i3,
                G1s[rd], G2s[rd], G3s[rd], G1s[wr], G2s[wr], G3s[wr],
                W1, b1, W2, b2, W3, b3, Wm, bm, Wl, bl,
                xnext, OB, do_head, do_g);
        else
            cells_kernel<false><<<BB * NN / PB, 512, 0, stream>>>(
                xq, xq_bs, xs, xs_bs, i1, i2, i3,
                G1s[rd], G2s[rd], G3s[rd], G1s[wr], G2s[wr], G3s[wr],
                W1, b1, W2, b2, W3, b3, Wm, bm, Wl, bl,
                xnext, OB, do_head, do_g);
    }
}

// Round 6
// 1156.155 us; speedup vs baseline: 3.5029x; 1.0268x over previous
//
#include <hip/hip_runtime.h>
#include <math.h>

#define BB 16
#define NN 512
#define KNN 8
#define SEQ 12
#define TQ 8            // knn: threads per query
#define QB 32           // knn: queries per block (TQ*QB = 256 threads)
#define PB 16           // cells: points per block

// ---------------------------------------------------------------------------
// KNN (unchanged — verified correct, conflict-free layout).
// ---------------------------------------------------------------------------
__global__ __launch_bounds__(256) void knn_kernel(
        const float* __restrict__ xq, int xq_bs,
        const float* __restrict__ xs, int xs_bs,
        int* __restrict__ idx1, int* __restrict__ idx2, int* __restrict__ idx3,
        float r2a, float r2b, float r2c, int warm) {
    __shared__ float s[NN * 3 + NN / 64];
    __shared__ float cd[QB][TQ][KNN + 1];
    __shared__ int   ci[QB][TQ][KNN + 1];
    int b = blockIdx.y;
    const float* xqp; const float* xsp; long iofs;
    if (warm) {
        int z = blockIdx.z;
        int qz = z < 5 ? z : 5;
        int sz = z - 1 < 0 ? 0 : z - 1;
        xqp = xq + (long)qz * NN * 3;
        xsp = xq + (long)sz * NN * 3;
        xs_bs = xq_bs;
        iofs = (long)z * BB * NN * KNN;
    } else {
        xqp = xq; xsp = xs; iofs = 0;
    }

    for (int j = threadIdx.x; j < NN; j += 256) {
        const float* p = xsp + (long)b * xs_bs + j * 3;
        int o = 3 * j + (j >> 6);
        s[o + 0] = p[0]; s[o + 1] = p[1]; s[o + 2] = p[2];
    }
    __syncthreads();

    int qi  = threadIdx.x / TQ;
    int sub = threadIdx.x % TQ;
    int n = blockIdx.x * QB + qi;
    const float* q = xqp + (long)b * xq_bs + n * 3;
    float qx = q[0], qy = q[1], qz2 = q[2];

    float bd[KNN];
    int   bi[KNN];
#pragma unroll
    for (int k = 0; k < KNN; ++k) { bd[k] = 1e30f; bi[k] = 0; }

    int j0 = sub * (NN / TQ);
    int sbase = 3 * j0 + sub;
#pragma unroll 4
    for (int jj = 0; jj < NN / TQ; ++jj) {
        float dx = s[sbase + 3 * jj + 0] - qx;
        float dy = s[sbase + 3 * jj + 1] - qy;
        float dz = s[sbase + 3 * jj + 2] - qz2;
        float d2 = fmaf(dx, dx, fmaf(dy, dy, dz * dz));
        if (d2 < bd[KNN - 1]) {
            bd[KNN - 1] = d2; bi[KNN - 1] = j0 + jj;
#pragma unroll
            for (int k = KNN - 1; k >= 1; --k) {
                if (bd[k] < bd[k - 1]) {
                    float td = bd[k]; bd[k] = bd[k - 1]; bd[k - 1] = td;
                    int   ti = bi[k]; bi[k] = bi[k - 1]; bi[k - 1] = ti;
                }
            }
        }
    }

#pragma unroll
    for (int k = 0; k < KNN; ++k) { cd[qi][sub][k] = bd[k]; ci[qi][sub][k] = bi[k]; }
    cd[qi][sub][KNN] = 1e30f; ci[qi][sub][KNN] = 0x7fffffff;
    __syncthreads();

    for (int stride = TQ / 2; stride >= 1; stride >>= 1) {
        if (sub < stride) {
            float rd[KNN]; int ri[KNN];
            int ia = 0, ib = 0;
#pragma unroll
            for (int k = 0; k < KNN; ++k) {
                float da = cd[qi][sub][ia], db = cd[qi][sub + stride][ib];
                int   ja = ci[qi][sub][ia], jb = ci[qi][sub + stride][ib];
                bool ta = (da < db) || (da == db && ja < jb);
                rd[k] = ta ? da : db; ri[k] = ta ? ja : jb;
                ia += ta ? 1 : 0; ib += ta ? 0 : 1;
            }
#pragma unroll
            for (int k = 0; k < KNN; ++k) { cd[qi][sub][k] = rd[k]; ci[qi][sub][k] = ri[k]; }
        }
        __syncthreads();
    }

    if (sub == 0) {
        long base = iofs + ((long)(b * NN + n)) * KNN;
        int i0 = ci[qi][0][0];
#pragma unroll
        for (int k = 0; k < KNN; ++k) {
            float d = cd[qi][0][k]; int j = ci[qi][0][k];
            idx1[base + k] = (d <= r2a) ? j : i0;
            idx2[base + k] = (d <= r2b) ? j : i0;
            idx3[base + k] = (d <= r2c) ? j : i0;
        }
    }
}

// ---------------------------------------------------------------------------
// Fused per-step cell pipeline, 512 threads, 16 points/block.
// Software-pipelined: G2 gathers prefetched behind P1b+P2; G3 gathers
// prefetched behind P3b+P4 (no barrier between issue and use).
// float4 LDS activation reads everywhere.
// ---------------------------------------------------------------------------
template<bool FIRST>
__global__ __launch_bounds__(512, 4) void cells_kernel(
        const float* __restrict__ xq, int xq_bs,
        const float* __restrict__ xs, int xs_bs,
        const int* __restrict__ i1, const int* __restrict__ i2,
        const int* __restrict__ i3,
        const float* __restrict__ G1p, const float* __restrict__ G2p,
        const float* __restrict__ G3p,
        float* __restrict__ G1n, float* __restrict__ G2n,
        float* __restrict__ G3n,
        const float* __restrict__ W1, const float* __restrict__ b1,
        const float* __restrict__ W2, const float* __restrict__ b2,
        const float* __restrict__ W3, const float* __restrict__ b3,
        const float* __restrict__ Wm, const float* __restrict__ bm,
        const float* __restrict__ Wl, const float* __restrict__ bl,
        float* __restrict__ xnext, int xn_bs, int do_head, int do_g) {
    __shared__ float s1s[PB][64];
    __shared__ float s2s[PB][128];
    __shared__ float s3b[PB][256];
    __shared__ float hs[PB][64];
    __shared__ float dsp[3][PB][KNN][3];
    __shared__ int   jss[3][PB][KNN];

    const int tid = threadIdx.x;
    const int blk = blockIdx.x;          // 0..511
    const int b   = blk >> 5;
    const int n0  = (blk & 31) << 4;
    const long row0 = (long)b * NN + n0;
    const long bN = (long)b * NN;

    // P0: neighbor indices + displacements for all 3 radii
    for (int t = tid; t < 3 * PB * KNN; t += 512) {
        int r = t >> 7, rem = t & 127, p = rem >> 3, k = rem & 7;
        const int* ix = (r == 0) ? i1 : ((r == 1) ? i2 : i3);
        int j = ix[(row0 + p) * KNN + k];
        jss[r][p][k] = j;
        const float* sp = xs + (long)b * xs_bs + j * 3;
        const float* qp = xq + (long)b * xq_bs + (n0 + p) * 3;
        dsp[r][p][k][0] = sp[0] - qp[0];
        dsp[r][p][k][1] = sp[1] - qp[1];
        dsp[r][p][k][2] = sp[2] - qp[2];
    }
    __syncthreads();

    // P1: cell1 combine -> s1s (G1 gathers issued up front, batched)
    {
        int co = tid & 63, q = tid >> 6;
        float g1r[2][KNN];
        if (!FIRST) {
#pragma unroll
            for (int r = 0; r < 2; ++r)
#pragma unroll
                for (int k = 0; k < KNN; ++k)
                    g1r[r][k] = G1p[(bN + jss[0][2 * q + r][k]) * 64 + co];
        }
        float wx = W1[co], wy = W1[64 + co], wz = W1[128 + co];
        float bz = b1[co];
#pragma unroll
        for (int r = 0; r < 2; ++r) {
            int p = 2 * q + r;
            float acc = -1e30f;
#pragma unroll
            for (int k = 0; k < KNN; ++k) {
                float v = fmaf(dsp[0][p][k][0], wx, bz);
                v = fmaf(dsp[0][p][k][1], wy, v);
                v = fmaf(dsp[0][p][k][2], wz, v);
                if (!FIRST) v += g1r[r][k];
                acc = fmaxf(acc, v);
            }
            s1s[p][co] = acc;
        }
    }
    __syncthreads();

    // ---- G2 prefetch: consumed in P3, hidden behind P1b + P2 ----
    float4 g2r[KNN];
    {
        int c4 = tid & 31, g = tid >> 5;
        if (!FIRST) {
#pragma unroll
            for (int k = 0; k < KNN; ++k)
                g2r[k] = ((const float4*)G2p)[(bN + jss[1][g][k]) * 32 + c4];
        }
    }

    // P1b: G1 next = s1s @ W1n
    if (do_g) {
        int co = tid & 63, q = tid >> 6;
        const float* W1n = W1 + 3 * 64;
        float a0 = 0.f, a1 = 0.f;
#pragma unroll 2
        for (int c = 0; c < 64; c += 4) {
            float4 x0 = *(const float4*)&s1s[2 * q][c];
            float4 x1 = *(const float4*)&s1s[2 * q + 1][c];
            float w0 = W1n[(c + 0) * 64 + co], w1 = W1n[(c + 1) * 64 + co];
            float w2 = W1n[(c + 2) * 64 + co], w3 = W1n[(c + 3) * 64 + co];
            a0 = fmaf(x0.x, w0, a0); a0 = fmaf(x0.y, w1, a0);
            a0 = fmaf(x0.z, w2, a0); a0 = fmaf(x0.w, w3, a0);
            a1 = fmaf(x1.x, w0, a1); a1 = fmaf(x1.y, w1, a1);
            a1 = fmaf(x1.z, w2, a1); a1 = fmaf(x1.w, w3, a1);
        }
        G1n[(row0 + 2 * q) * 64 + co] = a0;
        G1n[(row0 + 2 * q + 1) * 64 + co] = a1;
    }

    // P2+P3: base2 then combine2 in registers
    {
        int c4 = tid & 31, g = tid >> 5;
        const float4* W2f4 = (const float4*)(W2 + 3 * 128);
        float4 acc = ((const float4*)b2)[c4];
#pragma unroll 2
        for (int c = 0; c < 64; c += 4) {
            float4 x = *(const float4*)&s1s[g][c];
            float4 w0 = W2f4[(c + 0) * 32 + c4];
            float4 w1 = W2f4[(c + 1) * 32 + c4];
            float4 w2 = W2f4[(c + 2) * 32 + c4];
            float4 w3 = W2f4[(c + 3) * 32 + c4];
            acc.x = fmaf(x.x, w0.x, acc.x); acc.y = fmaf(x.x, w0.y, acc.y);
            acc.z = fmaf(x.x, w0.z, acc.z); acc.w = fmaf(x.x, w0.w, acc.w);
            acc.x = fmaf(x.y, w1.x, acc.x); acc.y = fmaf(x.y, w1.y, acc.y);
            acc.z = fmaf(x.y, w1.z, acc.z); acc.w = fmaf(x.y, w1.w, acc.w);
            acc.x = fmaf(x.z, w2.x, acc.x); acc.y = fmaf(x.z, w2.y, acc.y);
            acc.z = fmaf(x.z, w2.z, acc.z); acc.w = fmaf(x.z, w2.w, acc.w);
            acc.x = fmaf(x.w, w3.x, acc.x); acc.y = fmaf(x.w, w3.y, acc.y);
            acc.z = fmaf(x.w, w3.z, acc.z); acc.w = fmaf(x.w, w3.w, acc.w);
        }
        float4 wx = ((const float4*)W2)[c4];
        float4 wy = ((const float4*)(W2 + 128))[c4];
        float4 wz = ((const float4*)(W2 + 256))[c4];
        float4 m = make_float4(-1e30f, -1e30f, -1e30f, -1e30f);
#pragma unroll
        for (int k = 0; k < KNN; ++k) {
            float dx = dsp[1][g][k][0], dy = dsp[1][g][k][1], dz = dsp[1][g][k][2];
            float4 v;
            v.x = fmaf(dz, wz.x, fmaf(dy, wy.x, fmaf(dx, wx.x, acc.x)));
            v.y = fmaf(dz, wz.y, fmaf(dy, wy.y, fmaf(dx, wx.y, acc.y)));
            v.z = fmaf(dz, wz.z, fmaf(dy, wy.z, fmaf(dx, wx.z, acc.z)));
            v.w = fmaf(dz, wz.w, fmaf(dy, wy.w, fmaf(dx, wx.w, acc.w)));
            if (!FIRST) {
                v.x += g2r[k].x; v.y += g2r[k].y;
                v.z += g2r[k].z; v.w += g2r[k].w;
            }
            m.x = fmaxf(m.x, v.x); m.y = fmaxf(m.y, v.y);
            m.z = fmaxf(m.z, v.z); m.w = fmaxf(m.w, v.w);
        }
        *(float4*)&s2s[g][c4 * 4] = m;
    }
    __syncthreads();

    // ---- G3 prefetch: consumed in P5, hidden behind P3b + P4 ----
    float4 g3r[2][KNN];
    {
        int c4 = tid & 63, g = tid >> 6;
        if (!FIRST) {
#pragma unroll
            for (int r = 0; r < 2; ++r)
#pragma unroll
                for (int k = 0; k < KNN; ++k)
                    g3r[r][k] = ((const float4*)G3p)[(bN + jss[2][2 * g + r][k]) * 64 + c4];
        }
    }

    // P3b: G2 next = s2s @ W2n
    if (do_g) {
        int c4 = tid & 31, g = tid >> 5;
        const float4* W2n4 = (const float4*)(W2 + 67 * 128);
        float4 acc = make_float4(0.f, 0.f, 0.f, 0.f);
#pragma unroll 2
        for (int c = 0; c < 128; c += 4) {
            float4 x = *(const float4*)&s2s[g][c];
            float4 w0 = W2n4[(c + 0) * 32 + c4];
            float4 w1 = W2n4[(c + 1) * 32 + c4];
            float4 w2 = W2n4[(c + 2) * 32 + c4];
            float4 w3 = W2n4[(c + 3) * 32 + c4];
            acc.x = fmaf(x.x, w0.x, acc.x); acc.y = fmaf(x.x, w0.y, acc.y);
            acc.z = fmaf(x.x, w0.z, acc.z); acc.w = fmaf(x.x, w0.w, acc.w);
            acc.x = fmaf(x.y, w1.x, acc.x); acc.y = fmaf(x.y, w1.y, acc.y);
            acc.z = fmaf(x.y, w1.z, acc.z); acc.w = fmaf(x.y, w1.w, acc.w);
            acc.x = fmaf(x.z, w2.x, acc.x); acc.y = fmaf(x.z, w2.y, acc.y);
            acc.z = fmaf(x.z, w2.z, acc.z); acc.w = fmaf(x.z, w2.w, acc.w);
            acc.x = fmaf(x.w, w3.x, acc.x); acc.y = fmaf(x.w, w3.y, acc.y);
            acc.z = fmaf(x.w, w3.z, acc.z); acc.w = fmaf(x.w, w3.w, acc.w);
        }
        *(float4*)&G2n[(row0 + g) * 128 + c4 * 4] = acc;
    }

    // P4+P5: base3 then combine3 in registers
    {
        int c4 = tid & 63, g = tid >> 6;
        const float4* W3f4 = (const float4*)(W3 + 3 * 256);
        float4 bz4 = ((const float4*)b3)[c4];
        float4 a0 = bz4, a1 = bz4;
#pragma unroll 2
        for (int c = 0; c < 128; c += 4) {
            float4 x0 = *(const float4*)&s2s[2 * g][c];
            float4 x1 = *(const float4*)&s2s[2 * g + 1][c];
            float4 w0 = W3f4[(c + 0) * 64 + c4];
            float4 w1 = W3f4[(c + 1) * 64 + c4];
            float4 w2 = W3f4[(c + 2) * 64 + c4];
            float4 w3 = W3f4[(c + 3) * 64 + c4];
            a0.x = fmaf(x0.x, w0.x, a0.x); a0.y = fmaf(x0.x, w0.y, a0.y);
            a0.z = fmaf(x0.x, w0.z, a0.z); a0.w = fmaf(x0.x, w0.w, a0.w);
            a1.x = fmaf(x1.x, w0.x, a1.x); a1.y = fmaf(x1.x, w0.y, a1.y);
            a1.z = fmaf(x1.x, w0.z, a1.z); a1.w = fmaf(x1.x, w0.w, a1.w);
            a0.x = fmaf(x0.y, w1.x, a0.x); a0.y = fmaf(x0.y, w1.y, a0.y);
            a0.z = fmaf(x0.y, w1.z, a0.z); a0.w = fmaf(x0.y, w1.w, a0.w);
            a1.x = fmaf(x1.y, w1.x, a1.x); a1.y = fmaf(x1.y, w1.y, a1.y);
            a1.z = fmaf(x1.y, w1.z, a1.z); a1.w = fmaf(x1.y, w1.w, a1.w);
            a0.x = fmaf(x0.z, w2.x, a0.x); a0.y = fmaf(x0.z, w2.y, a0.y);
            a0.z = fmaf(x0.z, w2.z, a0.z); a0.w = fmaf(x0.z, w2.w, a0.w);
            a1.x = fmaf(x1.z, w2.x, a1.x); a1.y = fmaf(x1.z, w2.y, a1.y);
            a1.z = fmaf(x1.z, w2.z, a1.z); a1.w = fmaf(x1.z, w2.w, a1.w);
            a0.x = fmaf(x0.w, w3.x, a0.x); a0.y = fmaf(x0.w, w3.y, a0.y);
            a0.z = fmaf(x0.w, w3.z, a0.z); a0.w = fmaf(x0.w, w3.w, a0.w);
            a1.x = fmaf(x1.w, w3.x, a1.x); a1.y = fmaf(x1.w, w3.y, a1.y);
            a1.z = fmaf(x1.w, w3.z, a1.z); a1.w = fmaf(x1.w, w3.w, a1.w);
        }
        float4 wx = ((const float4*)W3)[c4];
        float4 wy = ((const float4*)(W3 + 256))[c4];
        float4 wz = ((const float4*)(W3 + 512))[c4];
#pragma unroll
        for (int r = 0; r < 2; ++r) {
            int p = 2 * g + r;
            float4 bse = r ? a1 : a0;
            float4 m = make_float4(-1e30f, -1e30f, -1e30f, -1e30f);
#pragma unroll
            for (int k = 0; k < KNN; ++k) {
                float dx = dsp[2][p][k][0], dy = dsp[2][p][k][1], dz = dsp[2][p][k][2];
                float4 v;
                v.x = fmaf(dz, wz.x, fmaf(dy, wy.x, fmaf(dx, wx.x, bse.x)));
                v.y = fmaf(dz, wz.y, fmaf(dy, wy.y, fmaf(dx, wx.y, bse.y)));
                v.z = fmaf(dz, wz.z, fmaf(dy, wy.z, fmaf(dx, wx.z, bse.z)));
                v.w = fmaf(dz, wz.w, fmaf(dy, wy.w, fmaf(dx, wx.w, bse.w)));
                if (!FIRST) {
                    v.x += g3r[r][k].x; v.y += g3r[r][k].y;
                    v.z += g3r[r][k].z; v.w += g3r[r][k].w;
                }
                m.x = fmaxf(m.x, v.x); m.y = fmaxf(m.y, v.y);
                m.z = fmaxf(m.z, v.z); m.w = fmaxf(m.w, v.w);
            }
            *(float4*)&s3b[p][c4 * 4] = m;
        }
    }
    __syncthreads();

    // P5b: G3 next = s3b @ W3n
    if (do_g) {
        int c4 = tid & 63, g = tid >> 6;
        const float4* W3n4 = (const float4*)(W3 + 131 * 256);
        float4 a0 = make_float4(0.f, 0.f, 0.f, 0.f);
        float4 a1 = a0;
#pragma unroll 2
        for (int c = 0; c < 256; c += 4) {
            float4 x0 = *(const float4*)&s3b[2 * g][c];
            float4 x1 = *(const float4*)&s3b[2 * g + 1][c];
            float4 w0 = W3n4[(c + 0) * 64 + c4];
            float4 w1 = W3n4[(c + 1) * 64 + c4];
            float4 w2 = W3n4[(c + 2) * 64 + c4];
            float4 w3 = W3n4[(c + 3) * 64 + c4];
            a0.x = fmaf(x0.x, w0.x, a0.x); a0.y = fmaf(x0.x, w0.y, a0.y);
            a0.z = fmaf(x0.x, w0.z, a0.z); a0.w = fmaf(x0.x, w0.w, a0.w);
            a1.x = fmaf(x1.x, w0.x, a1.x); a1.y = fmaf(x1.x, w0.y, a1.y);
            a1.z = fmaf(x1.x, w0.z, a1.z); a1.w = fmaf(x1.x, w0.w, a1.w);
            a0.x = fmaf(x0.y, w1.x, a0.x); a0.y = fmaf(x0.y, w1.y, a0.y);
            a0.z = fmaf(x0.y, w1.z, a0.z); a0.w = fmaf(x0.y, w1.w, a0.w);
            a1.x = fmaf(x1.y, w1.x, a1.x); a1.y = fmaf(x1.y, w1.y, a1.y);
            a1.z = fmaf(x1.y, w1.z, a1.z); a1.w = fmaf(x1.y, w1.w, a1.w);
            a0.x = fmaf(x0.z, w2.x, a0.x); a0.y = fmaf(x0.z, w2.y, a0.y);
            a0.z = fmaf(x0.z, w2.z, a0.z); a0.w = fmaf(x0.z, w2.w, a0.w);
            a1.x = fmaf(x1.z, w2.x, a1.x); a1.y = fmaf(x1.z, w2.y, a1.y);
            a1.z = fmaf(x1.z, w2.z, a1.z); a1.w = fmaf(x1.z, w2.w, a1.w);
            a0.x = fmaf(x0.w, w3.x, a0.x); a0.y = fmaf(x0.w, w3.y, a0.y);
            a0.z = fmaf(x0.w, w3.z, a0.z); a0.w = fmaf(x0.w, w3.w, a0.w);
            a1.x = fmaf(x1.w, w3.x, a1.x); a1.y = fmaf(x1.w, w3.y, a1.y);
            a1.z = fmaf(x1.w, w3.z, a1.z); a1.w = fmaf(x1.w, w3.w, a1.w);
        }
        *(float4*)&G3n[(row0 + 2 * g) * 256 + c4 * 4] = a0;
        *(float4*)&G3n[(row0 + 2 * g + 1) * 256 + c4 * 4] = a1;
    }

    // P6: prediction head
    if (do_head) {
        {
            int co = tid & 63, q = tid >> 6;
            float a0 = bm[co], a1 = a0;
#pragma unroll 2
            for (int c = 0; c < 256; c += 4) {
                float4 x0 = *(const float4*)&s3b[2 * q][c];
                float4 x1 = *(const float4*)&s3b[2 * q + 1][c];
                float w0 = Wm[(c + 0) * 64 + co], w1 = Wm[(c + 1) * 64 + co];
                float w2 = Wm[(c + 2) * 64 + co], w3 = Wm[(c + 3) * 64 + co];
                a0 = fmaf(x0.x, w0, a0); a0 = fmaf(x0.y, w1, a0);
                a0 = fmaf(x0.z, w2, a0); a0 = fmaf(x0.w, w3, a0);
                a1 = fmaf(x1.x, w0, a1); a1 = fmaf(x1.y, w1, a1);
                a1 = fmaf(x1.z, w2, a1); a1 = fmaf(x1.w, w3, a1);
            }
            hs[2 * q][co] = fmaxf(a0, 0.f);
            hs[2 * q + 1][co] = fmaxf(a1, 0.f);
        }
        __syncthreads();
        if (tid < PB * 3) {
            int p = tid / 3, d = tid % 3;
            float m = bl[d];
#pragma unroll 4
            for (int c = 0; c < 64; ++c)
                m = fmaf(hs[p][c], Wl[c * 3 + d], m);
            const float* qp = xq + (long)b * xq_bs + (n0 + p) * 3;
            xnext[(long)b * xn_bs + (n0 + p) * 3 + d] = qp[d] + m;
        }
    }
}

extern "C" void kernel_launch(void* const* d_in, const int* in_sizes, int n_in,
                              void* d_out, int out_size, void* d_ws, size_t ws_size,
                              hipStream_t stream) {
    const float* frames = (const float*)d_in[0];
    const float* W1 = (const float*)d_in[1]; const float* b1 = (const float*)d_in[2];
    const float* W2 = (const float*)d_in[3]; const float* b2 = (const float*)d_in[4];
    const float* W3 = (const float*)d_in[5]; const float* b3 = (const float*)d_in[6];
    const float* Wm = (const float*)d_in[7]; const float* bm = (const float*)d_in[8];
    const float* Wl = (const float*)d_in[9]; const float* bl = (const float*)d_in[10];
    float* out = (float*)d_out;

    float* ws = (float*)d_ws;
    float* G1s[2]; float* G2s[2]; float* G3s[2];
    for (int p = 0; p < 2; ++p) {
        G1s[p] = ws; ws += (size_t)BB * NN * 64;
        G2s[p] = ws; ws += (size_t)BB * NN * 128;
        G3s[p] = ws; ws += (size_t)BB * NN * 256;
    }
    const long BNK = (long)BB * NN * KNN;
    int* ip = (int*)ws;
    int* idx1w = ip; ip += 7 * BNK;
    int* idx2w = ip; ip += 7 * BNK;
    int* idx3w = ip; ip += 7 * BNK;

    double ra = 4.0 + 1e-6, rb = 8.0 + 1e-6, rc = 12.0 + 1e-6;
    float r2a = (float)(ra * ra), r2b = (float)(rb * rb), r2c = (float)(rc * rc);

    const int FB = SEQ * NN * 3;
    const int OB = 6 * NN * 3;

    knn_kernel<<<dim3(NN / QB, BB, 7), 256, 0, stream>>>(
        frames, FB, nullptr, 0, idx1w, idx2w, idx3w, r2a, r2b, r2c, 1);

    for (int t = 0; t < SEQ; ++t) {
        const float* xq; int xq_bs;
        const float* xs; int xs_bs;
        if (t < 6)       { xq = frames + (long)t * NN * 3;        xq_bs = FB; }
        else if (t == 6) { xq = frames + 5L * NN * 3;             xq_bs = FB; }
        else             { xq = out + (long)(t - 7) * NN * 3;     xq_bs = OB; }
        if (t == 0)      { xs = xq;                               xs_bs = xq_bs; }
        else if (t <= 6) { xs = frames + (long)(t - 1) * NN * 3;  xs_bs = FB; }
        else if (t == 7) { xs = frames + 5L * NN * 3;             xs_bs = FB; }
        else             { xs = out + (long)(t - 8) * NN * 3;     xs_bs = OB; }

        int slot = (t <= 6) ? t : 0;
        int* i1 = idx1w + slot * BNK;
        int* i2 = idx2w + slot * BNK;
        int* i3 = idx3w + slot * BNK;

        if (t >= 7)
            knn_kernel<<<dim3(NN / QB, BB, 1), 256, 0, stream>>>(
                xq, xq_bs, xs, xs_bs, i1, i2, i3, r2a, r2b, r2c, 0);

        int rd = t & 1, wr = (t + 1) & 1;
        int do_head = (t >= 6);
        int do_g = (t < SEQ - 1);
        float* xnext = do_head ? out + (long)(t - 6) * NN * 3 : nullptr;

        if (t == 0)
            cells_kernel<true><<<BB * NN / PB, 512, 0, stream>>>(
                xq, xq_bs, xs, xs_bs, i1, i2, i3,
                G1s[rd], G2s[rd], G3s[rd], G1s[wr], G2s[wr], G3s[wr],
                W1, b1, W2, b2, W3, b3, Wm, bm, Wl, bl,
                xnext, OB, do_head, do_g);
        else
            cells_kernel<false><<<BB * NN / PB, 512, 0, stream>>>(
                xq, xq_bs, xs, xs_bs, i1, i2, i3,
                G1s[rd], G2s[rd], G3s[rd], G1s[wr], G2s[wr], G3s[wr],
                W1, b1, W2, b2, W3, b3, Wm, bm, Wl, bl,
                xnext, OB, do_head, do_g);
    }
}

// Round 7
// 1133.625 us; speedup vs baseline: 3.5725x; 1.0199x over previous
//
#include <hip/hip_runtime.h>
#include <math.h>

#define BB 16
#define NN 512
#define KNN 8
#define SEQ 12
#define TQ 8            // knn: threads per query
#define QB 32           // knn: queries per block (TQ*QB = 256 threads)
#define PB 16           // cells: points per block

// ---------------------------------------------------------------------------
// KNN (unchanged — verified correct, conflict-free layout).
// ---------------------------------------------------------------------------
__global__ __launch_bounds__(256) void knn_kernel(
        const float* __restrict__ xq, int xq_bs,
        const float* __restrict__ xs, int xs_bs,
        int* __restrict__ idx1, int* __restrict__ idx2, int* __restrict__ idx3,
        float r2a, float r2b, float r2c, int warm) {
    __shared__ float s[NN * 3 + NN / 64];
    __shared__ float cd[QB][TQ][KNN + 1];
    __shared__ int   ci[QB][TQ][KNN + 1];
    int b = blockIdx.y;
    const float* xqp; const float* xsp; long iofs;
    if (warm) {
        int z = blockIdx.z;
        int qz = z < 5 ? z : 5;
        int sz = z - 1 < 0 ? 0 : z - 1;
        xqp = xq + (long)qz * NN * 3;
        xsp = xq + (long)sz * NN * 3;
        xs_bs = xq_bs;
        iofs = (long)z * BB * NN * KNN;
    } else {
        xqp = xq; xsp = xs; iofs = 0;
    }

    for (int j = threadIdx.x; j < NN; j += 256) {
        const float* p = xsp + (long)b * xs_bs + j * 3;
        int o = 3 * j + (j >> 6);
        s[o + 0] = p[0]; s[o + 1] = p[1]; s[o + 2] = p[2];
    }
    __syncthreads();

    int qi  = threadIdx.x / TQ;
    int sub = threadIdx.x % TQ;
    int n = blockIdx.x * QB + qi;
    const float* q = xqp + (long)b * xq_bs + n * 3;
    float qx = q[0], qy = q[1], qz2 = q[2];

    float bd[KNN];
    int   bi[KNN];
#pragma unroll
    for (int k = 0; k < KNN; ++k) { bd[k] = 1e30f; bi[k] = 0; }

    int j0 = sub * (NN / TQ);
    int sbase = 3 * j0 + sub;
#pragma unroll 4
    for (int jj = 0; jj < NN / TQ; ++jj) {
        float dx = s[sbase + 3 * jj + 0] - qx;
        float dy = s[sbase + 3 * jj + 1] - qy;
        float dz = s[sbase + 3 * jj + 2] - qz2;
        float d2 = fmaf(dx, dx, fmaf(dy, dy, dz * dz));
        if (d2 < bd[KNN - 1]) {
            bd[KNN - 1] = d2; bi[KNN - 1] = j0 + jj;
#pragma unroll
            for (int k = KNN - 1; k >= 1; --k) {
                if (bd[k] < bd[k - 1]) {
                    float td = bd[k]; bd[k] = bd[k - 1]; bd[k - 1] = td;
                    int   ti = bi[k]; bi[k] = bi[k - 1]; bi[k - 1] = ti;
                }
            }
        }
    }

#pragma unroll
    for (int k = 0; k < KNN; ++k) { cd[qi][sub][k] = bd[k]; ci[qi][sub][k] = bi[k]; }
    cd[qi][sub][KNN] = 1e30f; ci[qi][sub][KNN] = 0x7fffffff;
    __syncthreads();

    for (int stride = TQ / 2; stride >= 1; stride >>= 1) {
        if (sub < stride) {
            float rd[KNN]; int ri[KNN];
            int ia = 0, ib = 0;
#pragma unroll
            for (int k = 0; k < KNN; ++k) {
                float da = cd[qi][sub][ia], db = cd[qi][sub + stride][ib];
                int   ja = ci[qi][sub][ia], jb = ci[qi][sub + stride][ib];
                bool ta = (da < db) || (da == db && ja < jb);
                rd[k] = ta ? da : db; ri[k] = ta ? ja : jb;
                ia += ta ? 1 : 0; ib += ta ? 0 : 1;
            }
#pragma unroll
            for (int k = 0; k < KNN; ++k) { cd[qi][sub][k] = rd[k]; ci[qi][sub][k] = ri[k]; }
        }
        __syncthreads();
    }

    if (sub == 0) {
        long base = iofs + ((long)(b * NN + n)) * KNN;
        int i0 = ci[qi][0][0];
#pragma unroll
        for (int k = 0; k < KNN; ++k) {
            float d = cd[qi][0][k]; int j = ci[qi][0][k];
            idx1[base + k] = (d <= r2a) ? j : i0;
            idx2[base + k] = (d <= r2b) ? j : i0;
            idx3[base + k] = (d <= r2c) ? j : i0;
        }
    }
}

// ---------------------------------------------------------------------------
// Kernel A: gathers + combines + bases + head. Writes s1/s2/s3 to global for
// the separate G-GEMM kernel. 512 threads, 16 points/block, 512 blocks.
// ---------------------------------------------------------------------------
template<bool FIRST>
__global__ __launch_bounds__(512, 4) void cells_kernel(
        const float* __restrict__ xq, int xq_bs,
        const float* __restrict__ xs, int xs_bs,
        const int* __restrict__ i1, const int* __restrict__ i2,
        const int* __restrict__ i3,
        const float* __restrict__ G1p, const float* __restrict__ G2p,
        const float* __restrict__ G3p,
        float* __restrict__ s1g, float* __restrict__ s2g,
        float* __restrict__ s3g,
        const float* __restrict__ W1, const float* __restrict__ b1,
        const float* __restrict__ W2, const float* __restrict__ b2,
        const float* __restrict__ W3, const float* __restrict__ b3,
        const float* __restrict__ Wm, const float* __restrict__ bm,
        const float* __restrict__ Wl, const float* __restrict__ bl,
        float* __restrict__ xnext, int xn_bs, int do_head) {
    __shared__ float s1s[PB][64];
    __shared__ float s2s[PB][128];
    __shared__ float s3b[PB][256];
    __shared__ float hs[PB][64];
    __shared__ float dsp[3][PB][KNN][3];
    __shared__ int   jss[3][PB][KNN];

    const int tid = threadIdx.x;
    const int blk = blockIdx.x;          // 0..511
    const int b   = blk >> 5;
    const int n0  = (blk & 31) << 4;
    const long row0 = (long)b * NN + n0;
    const long bN = (long)b * NN;

    // P0: neighbor indices + displacements for all 3 radii
    for (int t = tid; t < 3 * PB * KNN; t += 512) {
        int r = t >> 7, rem = t & 127, p = rem >> 3, k = rem & 7;
        const int* ix = (r == 0) ? i1 : ((r == 1) ? i2 : i3);
        int j = ix[(row0 + p) * KNN + k];
        jss[r][p][k] = j;
        const float* sp = xs + (long)b * xs_bs + j * 3;
        const float* qp = xq + (long)b * xq_bs + (n0 + p) * 3;
        dsp[r][p][k][0] = sp[0] - qp[0];
        dsp[r][p][k][1] = sp[1] - qp[1];
        dsp[r][p][k][2] = sp[2] - qp[2];
    }
    __syncthreads();

    // P1: cell1 combine -> s1s + global store
    {
        int co = tid & 63, q = tid >> 6;
        float g1r[2][KNN];
        if (!FIRST) {
#pragma unroll
            for (int r = 0; r < 2; ++r)
#pragma unroll
                for (int k = 0; k < KNN; ++k)
                    g1r[r][k] = G1p[(bN + jss[0][2 * q + r][k]) * 64 + co];
        }
        float wx = W1[co], wy = W1[64 + co], wz = W1[128 + co];
        float bz = b1[co];
#pragma unroll
        for (int r = 0; r < 2; ++r) {
            int p = 2 * q + r;
            float acc = -1e30f;
#pragma unroll
            for (int k = 0; k < KNN; ++k) {
                float v = fmaf(dsp[0][p][k][0], wx, bz);
                v = fmaf(dsp[0][p][k][1], wy, v);
                v = fmaf(dsp[0][p][k][2], wz, v);
                if (!FIRST) v += g1r[r][k];
                acc = fmaxf(acc, v);
            }
            s1s[p][co] = acc;
            s1g[(row0 + p) * 64 + co] = acc;
        }
    }
    __syncthreads();

    // G2 gathers prefetched here, consumed in combine2
    float4 g2r[KNN];
    {
        int c4 = tid & 31, g = tid >> 5;
        if (!FIRST) {
#pragma unroll
            for (int k = 0; k < KNN; ++k)
                g2r[k] = ((const float4*)G2p)[(bN + jss[1][g][k]) * 32 + c4];
        }
    }

    // P2+P3: base2 then combine2 in registers -> s2s + global store
    {
        int c4 = tid & 31, g = tid >> 5;
        const float4* W2f4 = (const float4*)(W2 + 3 * 128);
        float4 acc = ((const float4*)b2)[c4];
#pragma unroll 2
        for (int c = 0; c < 64; c += 4) {
            float4 x = *(const float4*)&s1s[g][c];
            float4 w0 = W2f4[(c + 0) * 32 + c4];
            float4 w1 = W2f4[(c + 1) * 32 + c4];
            float4 w2 = W2f4[(c + 2) * 32 + c4];
            float4 w3 = W2f4[(c + 3) * 32 + c4];
            acc.x = fmaf(x.x, w0.x, acc.x); acc.y = fmaf(x.x, w0.y, acc.y);
            acc.z = fmaf(x.x, w0.z, acc.z); acc.w = fmaf(x.x, w0.w, acc.w);
            acc.x = fmaf(x.y, w1.x, acc.x); acc.y = fmaf(x.y, w1.y, acc.y);
            acc.z = fmaf(x.y, w1.z, acc.z); acc.w = fmaf(x.y, w1.w, acc.w);
            acc.x = fmaf(x.z, w2.x, acc.x); acc.y = fmaf(x.z, w2.y, acc.y);
            acc.z = fmaf(x.z, w2.z, acc.z); acc.w = fmaf(x.z, w2.w, acc.w);
            acc.x = fmaf(x.w, w3.x, acc.x); acc.y = fmaf(x.w, w3.y, acc.y);
            acc.z = fmaf(x.w, w3.z, acc.z); acc.w = fmaf(x.w, w3.w, acc.w);
        }
        float4 wx = ((const float4*)W2)[c4];
        float4 wy = ((const float4*)(W2 + 128))[c4];
        float4 wz = ((const float4*)(W2 + 256))[c4];
        float4 m = make_float4(-1e30f, -1e30f, -1e30f, -1e30f);
#pragma unroll
        for (int k = 0; k < KNN; ++k) {
            float dx = dsp[1][g][k][0], dy = dsp[1][g][k][1], dz = dsp[1][g][k][2];
            float4 v;
            v.x = fmaf(dz, wz.x, fmaf(dy, wy.x, fmaf(dx, wx.x, acc.x)));
            v.y = fmaf(dz, wz.y, fmaf(dy, wy.y, fmaf(dx, wx.y, acc.y)));
            v.z = fmaf(dz, wz.z, fmaf(dy, wy.z, fmaf(dx, wx.z, acc.z)));
            v.w = fmaf(dz, wz.w, fmaf(dy, wy.w, fmaf(dx, wx.w, acc.w)));
            if (!FIRST) {
                v.x += g2r[k].x; v.y += g2r[k].y;
                v.z += g2r[k].z; v.w += g2r[k].w;
            }
            m.x = fmaxf(m.x, v.x); m.y = fmaxf(m.y, v.y);
            m.z = fmaxf(m.z, v.z); m.w = fmaxf(m.w, v.w);
        }
        *(float4*)&s2s[g][c4 * 4] = m;
        *(float4*)&s2g[(row0 + g) * 128 + c4 * 4] = m;
    }
    __syncthreads();

    // G3 gathers prefetched here, consumed in combine3
    float4 g3r[2][KNN];
    {
        int c4 = tid & 63, g = tid >> 6;
        if (!FIRST) {
#pragma unroll
            for (int r = 0; r < 2; ++r)
#pragma unroll
                for (int k = 0; k < KNN; ++k)
                    g3r[r][k] = ((const float4*)G3p)[(bN + jss[2][2 * g + r][k]) * 64 + c4];
        }
    }

    // P4+P5: base3 then combine3 in registers -> s3b + global store
    {
        int c4 = tid & 63, g = tid >> 6;
        const float4* W3f4 = (const float4*)(W3 + 3 * 256);
        float4 bz4 = ((const float4*)b3)[c4];
        float4 a0 = bz4, a1 = bz4;
#pragma unroll 2
        for (int c = 0; c < 128; c += 4) {
            float4 x0 = *(const float4*)&s2s[2 * g][c];
            float4 x1 = *(const float4*)&s2s[2 * g + 1][c];
            float4 w0 = W3f4[(c + 0) * 64 + c4];
            float4 w1 = W3f4[(c + 1) * 64 + c4];
            float4 w2 = W3f4[(c + 2) * 64 + c4];
            float4 w3 = W3f4[(c + 3) * 64 + c4];
            a0.x = fmaf(x0.x, w0.x, a0.x); a0.y = fmaf(x0.x, w0.y, a0.y);
            a0.z = fmaf(x0.x, w0.z, a0.z); a0.w = fmaf(x0.x, w0.w, a0.w);
            a1.x = fmaf(x1.x, w0.x, a1.x); a1.y = fmaf(x1.x, w0.y, a1.y);
            a1.z = fmaf(x1.x, w0.z, a1.z); a1.w = fmaf(x1.x, w0.w, a1.w);
            a0.x = fmaf(x0.y, w1.x, a0.x); a0.y = fmaf(x0.y, w1.y, a0.y);
            a0.z = fmaf(x0.y, w1.z, a0.z); a0.w = fmaf(x0.y, w1.w, a0.w);
            a1.x = fmaf(x1.y, w1.x, a1.x); a1.y = fmaf(x1.y, w1.y, a1.y);
            a1.z = fmaf(x1.y, w1.z, a1.z); a1.w = fmaf(x1.y, w1.w, a1.w);
            a0.x = fmaf(x0.z, w2.x, a0.x); a0.y = fmaf(x0.z, w2.y, a0.y);
            a0.z = fmaf(x0.z, w2.z, a0.z); a0.w = fmaf(x0.z, w2.w, a0.w);
            a1.x = fmaf(x1.z, w2.x, a1.x); a1.y = fmaf(x1.z, w2.y, a1.y);
            a1.z = fmaf(x1.z, w2.z, a1.z); a1.w = fmaf(x1.z, w2.w, a1.w);
            a0.x = fmaf(x0.w, w3.x, a0.x); a0.y = fmaf(x0.w, w3.y, a0.y);
            a0.z = fmaf(x0.w, w3.z, a0.z); a0.w = fmaf(x0.w, w3.w, a0.w);
            a1.x = fmaf(x1.w, w3.x, a1.x); a1.y = fmaf(x1.w, w3.y, a1.y);
            a1.z = fmaf(x1.w, w3.z, a1.z); a1.w = fmaf(x1.w, w3.w, a1.w);
        }
        float4 wx = ((const float4*)W3)[c4];
        float4 wy = ((const float4*)(W3 + 256))[c4];
        float4 wz = ((const float4*)(W3 + 512))[c4];
#pragma unroll
        for (int r = 0; r < 2; ++r) {
            int p = 2 * g + r;
            float4 bse = r ? a1 : a0;
            float4 m = make_float4(-1e30f, -1e30f, -1e30f, -1e30f);
#pragma unroll
            for (int k = 0; k < KNN; ++k) {
                float dx = dsp[2][p][k][0], dy = dsp[2][p][k][1], dz = dsp[2][p][k][2];
                float4 v;
                v.x = fmaf(dz, wz.x, fmaf(dy, wy.x, fmaf(dx, wx.x, bse.x)));
                v.y = fmaf(dz, wz.y, fmaf(dy, wy.y, fmaf(dx, wx.y, bse.y)));
                v.z = fmaf(dz, wz.z, fmaf(dy, wy.z, fmaf(dx, wx.z, bse.z)));
                v.w = fmaf(dz, wz.w, fmaf(dy, wy.w, fmaf(dx, wx.w, bse.w)));
                if (!FIRST) {
                    v.x += g3r[r][k].x; v.y += g3r[r][k].y;
                    v.z += g3r[r][k].z; v.w += g3r[r][k].w;
                }
                m.x = fmaxf(m.x, v.x); m.y = fmaxf(m.y, v.y);
                m.z = fmaxf(m.z, v.z); m.w = fmaxf(m.w, v.w);
            }
            *(float4*)&s3b[p][c4 * 4] = m;
            *(float4*)&s3g[(row0 + p) * 256 + c4 * 4] = m;
        }
    }

    // P6: prediction head
    if (do_head) {
        __syncthreads();
        {
            int co = tid & 63, q = tid >> 6;
            float a0 = bm[co], a1 = a0;
#pragma unroll 2
            for (int c = 0; c < 256; c += 4) {
                float4 x0 = *(const float4*)&s3b[2 * q][c];
                float4 x1 = *(const float4*)&s3b[2 * q + 1][c];
                float w0 = Wm[(c + 0) * 64 + co], w1 = Wm[(c + 1) * 64 + co];
                float w2 = Wm[(c + 2) * 64 + co], w3 = Wm[(c + 3) * 64 + co];
                a0 = fmaf(x0.x, w0, a0); a0 = fmaf(x0.y, w1, a0);
                a0 = fmaf(x0.z, w2, a0); a0 = fmaf(x0.w, w3, a0);
                a1 = fmaf(x1.x, w0, a1); a1 = fmaf(x1.y, w1, a1);
                a1 = fmaf(x1.z, w2, a1); a1 = fmaf(x1.w, w3, a1);
            }
            hs[2 * q][co] = fmaxf(a0, 0.f);
            hs[2 * q + 1][co] = fmaxf(a1, 0.f);
        }
        __syncthreads();
        if (tid < PB * 3) {
            int p = tid / 3, d = tid % 3;
            float m = bl[d];
#pragma unroll 4
            for (int c = 0; c < 64; ++c)
                m = fmaf(hs[p][c], Wl[c * 3 + d], m);
            const float* qp = xq + (long)b * xq_bs + (n0 + p) * 3;
            xnext[(long)b * xn_bs + (n0 + p) * 3 + d] = qp[d] + m;
        }
    }
}

// ---------------------------------------------------------------------------
// Kernel B: the three G-GEMMs as proper tiled GEMMs. 64x64 output tile per
// block, 256 threads, 4x4 register tile/thread, X staged in LDS by 64-K
// chunks (stride 68 kills bank conflicts), weight slice streams from L1/L2.
// ---------------------------------------------------------------------------
template<int K, int COUT>
__device__ __forceinline__ void gemm64(const float* __restrict__ X,
                                       const float* __restrict__ W,
                                       float* __restrict__ Y,
                                       int rb, int cb, int tid, float* Xs) {
    const long row0 = (long)rb * 64;
    const int c0 = cb * 64;
    const int tx = tid & 15, ty = tid >> 4;
    float4 a0 = make_float4(0.f, 0.f, 0.f, 0.f);
    float4 a1 = a0, a2 = a0, a3 = a0;

    for (int k0 = 0; k0 < K; k0 += 64) {
        if (k0) __syncthreads();
#pragma unroll
        for (int i = 0; i < 4; ++i) {
            int f = tid + i * 256;       // 0..1023
            int row = f >> 4, c4 = f & 15;
            *(float4*)&Xs[row * 68 + c4 * 4] =
                *(const float4*)&X[(row0 + row) * K + k0 + c4 * 4];
        }
        __syncthreads();
#pragma unroll 4
        for (int k = 0; k < 64; k += 4) {
            float4 x0 = *(const float4*)&Xs[(4 * ty + 0) * 68 + k];
            float4 x1 = *(const float4*)&Xs[(4 * ty + 1) * 68 + k];
            float4 x2 = *(const float4*)&Xs[(4 * ty + 2) * 68 + k];
            float4 x3 = *(const float4*)&Xs[(4 * ty + 3) * 68 + k];
#pragma unroll
            for (int kk = 0; kk < 4; ++kk) {
                float4 w = *(const float4*)&W[(long)(k0 + k + kk) * COUT + c0 + 4 * tx];
                float f0 = (&x0.x)[kk], f1 = (&x1.x)[kk];
                float f2 = (&x2.x)[kk], f3 = (&x3.x)[kk];
                a0.x = fmaf(f0, w.x, a0.x); a0.y = fmaf(f0, w.y, a0.y);
                a0.z = fmaf(f0, w.z, a0.z); a0.w = fmaf(f0, w.w, a0.w);
                a1.x = fmaf(f1, w.x, a1.x); a1.y = fmaf(f1, w.y, a1.y);
                a1.z = fmaf(f1, w.z, a1.z); a1.w = fmaf(f1, w.w, a1.w);
                a2.x = fmaf(f2, w.x, a2.x); a2.y = fmaf(f2, w.y, a2.y);
                a2.z = fmaf(f2, w.z, a2.z); a2.w = fmaf(f2, w.w, a2.w);
                a3.x = fmaf(f3, w.x, a3.x); a3.y = fmaf(f3, w.y, a3.y);
                a3.z = fmaf(f3, w.z, a3.z); a3.w = fmaf(f3, w.w, a3.w);
            }
        }
    }
    *(float4*)&Y[(row0 + 4 * ty + 0) * COUT + c0 + 4 * tx] = a0;
    *(float4*)&Y[(row0 + 4 * ty + 1) * COUT + c0 + 4 * tx] = a1;
    *(float4*)&Y[(row0 + 4 * ty + 2) * COUT + c0 + 4 * tx] = a2;
    *(float4*)&Y[(row0 + 4 * ty + 3) * COUT + c0 + 4 * tx] = a3;
}

__global__ __launch_bounds__(256, 4) void gemmG_kernel(
        const float* __restrict__ s1, const float* __restrict__ s2,
        const float* __restrict__ s3,
        const float* __restrict__ W1n, const float* __restrict__ W2n,
        const float* __restrict__ W3n,
        float* __restrict__ G1, float* __restrict__ G2,
        float* __restrict__ G3) {
    __shared__ float Xs[64 * 68];
    int bx = blockIdx.x, tid = threadIdx.x;
    if (bx < 512)
        gemm64<256, 256>(s3, W3n, G3, bx >> 2, bx & 3, tid, Xs);
    else if (bx < 768)
        gemm64<128, 128>(s2, W2n, G2, (bx - 512) >> 1, (bx - 512) & 1, tid, Xs);
    else
        gemm64<64, 64>(s1, W1n, G1, bx - 768, 0, tid, Xs);
}

extern "C" void kernel_launch(void* const* d_in, const int* in_sizes, int n_in,
                              void* d_out, int out_size, void* d_ws, size_t ws_size,
                              hipStream_t stream) {
    const float* frames = (const float*)d_in[0];
    const float* W1 = (const float*)d_in[1]; const float* b1 = (const float*)d_in[2];
    const float* W2 = (const float*)d_in[3]; const float* b2 = (const float*)d_in[4];
    const float* W3 = (const float*)d_in[5]; const float* b3 = (const float*)d_in[6];
    const float* Wm = (const float*)d_in[7]; const float* bm = (const float*)d_in[8];
    const float* Wl = (const float*)d_in[9]; const float* bl = (const float*)d_in[10];
    float* out = (float*)d_out;

    float* ws = (float*)d_ws;
    float* G1b = ws; ws += (size_t)BB * NN * 64;
    float* G2b = ws; ws += (size_t)BB * NN * 128;
    float* G3b = ws; ws += (size_t)BB * NN * 256;
    float* s1b = ws; ws += (size_t)BB * NN * 64;
    float* s2b = ws; ws += (size_t)BB * NN * 128;
    float* s3c = ws; ws += (size_t)BB * NN * 256;
    const long BNK = (long)BB * NN * KNN;
    int* ip = (int*)ws;
    int* idx1w = ip; ip += 7 * BNK;
    int* idx2w = ip; ip += 7 * BNK;
    int* idx3w = ip; ip += 7 * BNK;

    double ra = 4.0 + 1e-6, rb = 8.0 + 1e-6, rc = 12.0 + 1e-6;
    float r2a = (float)(ra * ra), r2b = (float)(rb * rb), r2c = (float)(rc * rc);

    const int FB = SEQ * NN * 3;
    const int OB = 6 * NN * 3;

    knn_kernel<<<dim3(NN / QB, BB, 7), 256, 0, stream>>>(
        frames, FB, nullptr, 0, idx1w, idx2w, idx3w, r2a, r2b, r2c, 1);

    for (int t = 0; t < SEQ; ++t) {
        const float* xq; int xq_bs;
        const float* xs; int xs_bs;
        if (t < 6)       { xq = frames + (long)t * NN * 3;        xq_bs = FB; }
        else if (t == 6) { xq = frames + 5L * NN * 3;             xq_bs = FB; }
        else             { xq = out + (long)(t - 7) * NN * 3;     xq_bs = OB; }
        if (t == 0)      { xs = xq;                               xs_bs = xq_bs; }
        else if (t <= 6) { xs = frames + (long)(t - 1) * NN * 3;  xs_bs = FB; }
        else if (t == 7) { xs = frames + 5L * NN * 3;             xs_bs = FB; }
        else             { xs = out + (long)(t - 8) * NN * 3;     xs_bs = OB; }

        int slot = (t <= 6) ? t : 0;
        int* i1 = idx1w + slot * BNK;
        int* i2 = idx2w + slot * BNK;
        int* i3 = idx3w + slot * BNK;

        if (t >= 7)
            knn_kernel<<<dim3(NN / QB, BB, 1), 256, 0, stream>>>(
                xq, xq_bs, xs, xs_bs, i1, i2, i3, r2a, r2b, r2c, 0);

        int do_head = (t >= 6);
        float* xnext = do_head ? out + (long)(t - 6) * NN * 3 : nullptr;

        if (t == 0)
            cells_kernel<true><<<BB * NN / PB, 512, 0, stream>>>(
                xq, xq_bs, xs, xs_bs, i1, i2, i3,
                G1b, G2b, G3b, s1b, s2b, s3c,
                W1, b1, W2, b2, W3, b3, Wm, bm, Wl, bl,
                xnext, OB, do_head);
        else
            cells_kernel<false><<<BB * NN / PB, 512, 0, stream>>>(
                xq, xq_bs, xs, xs_bs, i1, i2, i3,
                G1b, G2b, G3b, s1b, s2b, s3c,
                W1, b1, W2, b2, W3, b3, Wm, bm, Wl, bl,
                xnext, OB, do_head);

        // G for step t+1 (A_t has fully consumed G_t before B_t overwrites)
        if (t < SEQ - 1)
            gemmG_kernel<<<896, 256, 0, stream>>>(
                s1b, s2b, s3c,
                W1 + 3 * 64, W2 + 67 * 128, W3 + 131 * 256,
                G1b, G2b, G3b);
    }
}